// Round 8
// baseline (458.070 us; speedup 1.0000x reference)
//
#include <hip/hip_runtime.h>
#include <math.h>

#define NEG_SLOPE 0.2f
#define BN_EPS 1e-5f

typedef __attribute__((ext_vector_type(8))) short bf16x8;
typedef __attribute__((ext_vector_type(4))) float f32x4;

static __device__ __forceinline__ unsigned short f2bf(float f){
    unsigned u = __float_as_uint(f);
    u += 0x7FFFu + ((u >> 16) & 1u);          // round-to-nearest-even
    return (unsigned short)(u >> 16);
}
static __device__ __forceinline__ float bf2f(unsigned short v){
    return __uint_as_float((unsigned)v << 16);
}

// async global->LDS, 16B/lane; LDS dest wave-uniform base + lane*16
static __device__ __forceinline__ void gload_lds16(const void* g, void* l){
    __builtin_amdgcn_global_load_lds(
        (const __attribute__((address_space(1))) void*)g,
        (__attribute__((address_space(3))) void*)l, 16, 0, 0);
}

// ---- fp32 -> (hi, lo) bf16 planes, elementwise ----
__global__ void conv_hilo_kernel(const float* __restrict__ x,
                                 unsigned short* __restrict__ hi,
                                 unsigned short* __restrict__ lo, int n4)
{
    int i = blockIdx.x * 256 + threadIdx.x;
    if (i >= n4) return;
    const float4 v = ((const float4*)x)[i];
    ushort4 h4, l4;
    h4.x = f2bf(v.x); l4.x = f2bf(v.x - bf2f(h4.x));
    h4.y = f2bf(v.y); l4.y = f2bf(v.y - bf2f(h4.y));
    h4.z = f2bf(v.z); l4.z = f2bf(v.z - bf2f(h4.z));
    h4.w = f2bf(v.w); l4.w = f2bf(v.w - bf2f(h4.w));
    ((ushort4*)hi)[i] = h4; ((ushort4*)lo)[i] = l4;
}

// ---- W [K][256] fp32 -> MFMA B-fragment layout, hi/lo bf16 planes ----
// out index o = (((kt*16+ct)*64+lane)*8+j);  k = kt*32+8*(lane>>4)+j, col = ct*16+(lane&15)
__global__ void repack_w_kernel(const float* __restrict__ W,
                                unsigned short* __restrict__ wbhi,
                                unsigned short* __restrict__ wblo)
{
    const int o = blockIdx.x * 256 + threadIdx.x;
    const int j = o & 7, ln = (o >> 3) & 63, ct = (o >> 9) & 15, kt = o >> 13;
    const int k = kt * 32 + 8 * (ln >> 4) + j;
    const int col = ct * 16 + (ln & 15);
    const float v = W[k * 256 + col];
    const unsigned short hb = f2bf(v);
    wbhi[o] = hb; wblo[o] = f2bf(v - bf2f(hb));
}

// =========================================================================
// MFMA GEMM h = x @ W ([N,K]@[K,256]) + per-head alpha reductions.
// Block = 256 thr = 4 waves = 64-node tile. Wave w owns col-tiles w*4..w*4+3
// (= head w). 3-pass hi/lo MFMA into shared fp32 acc. K-step = 32.
// C/D mapping (verified): col=lane&15, row=(lane>>4)*4+reg.
// h output written HEAD-MAJOR: hh[head][node][64ch] bf16.
// =========================================================================
template<int K>
__global__ __launch_bounds__(256) void mfma_gemm_alpha(
    const unsigned short* __restrict__ xhi, const unsigned short* __restrict__ xlo,
    const unsigned short* __restrict__ wbhi, const unsigned short* __restrict__ wblo,
    const float* __restrict__ a_s, const float* __restrict__ a_d,
    unsigned short* __restrict__ hout,
    float* __restrict__ asrc, float* __restrict__ adst, int N)
{
    __shared__ unsigned short xa[8][512];     // [rt*2+plane][lane*8] A-frags
    __shared__ unsigned short wb[32][512];    // [ct*2+plane][lane*8] B-frags
    const int t = threadIdx.x, lane = t & 63, wid = t >> 6;
    const int n0 = blockIdx.x * 64;

    f32x4 acc[4][4];
#pragma unroll
    for (int rt = 0; rt < 4; ++rt)
#pragma unroll
        for (int q = 0; q < 4; ++q) acc[rt][q] = (f32x4){0.f, 0.f, 0.f, 0.f};

    for (int kt = 0; kt < K / 32; ++kt){
        __syncthreads();                      // previous iteration reads done
        // stage A-frags: 8 x 1KB, wave wid issues 2
#pragma unroll
        for (int ii = 0; ii < 2; ++ii){
            const int i = wid * 2 + ii;
            const int rt = i >> 1, plane = i & 1;
            int node = n0 + rt * 16 + (lane & 15);
            if (node > N - 1) node = N - 1;   // clamp; results discarded later
            const unsigned short* src = (plane ? xlo : xhi)
                + (size_t)node * K + kt * 32 + 8 * (lane >> 4);
            gload_lds16(src, &xa[i][0]);
        }
        // stage B-frags: 32 x 1KB, wave wid issues 8 (linear, coalesced)
#pragma unroll
        for (int ii = 0; ii < 8; ++ii){
            const int i = wid * 8 + ii;
            const int ct = i >> 1, plane = i & 1;
            const unsigned short* base = plane ? wblo : wbhi;
            gload_lds16(base + ((size_t)(kt * 16 + ct) * 64 + lane) * 8, &wb[i][0]);
        }
        __syncthreads();                      // drains vmcnt (incl. lds loads)

        bf16x8 a[4][2];
#pragma unroll
        for (int rt = 0; rt < 4; ++rt)
#pragma unroll
            for (int pl = 0; pl < 2; ++pl)
                a[rt][pl] = *(const bf16x8*)&xa[rt * 2 + pl][lane * 8];

#pragma unroll
        for (int q = 0; q < 4; ++q){
            const int cti = wid * 4 + q;
            const bf16x8 bhi = *(const bf16x8*)&wb[cti * 2 + 0][lane * 8];
            const bf16x8 blo = *(const bf16x8*)&wb[cti * 2 + 1][lane * 8];
#pragma unroll
            for (int rt = 0; rt < 4; ++rt){
                acc[rt][q] = __builtin_amdgcn_mfma_f32_16x16x32_bf16(a[rt][0], bhi, acc[rt][q], 0, 0, 0);
                acc[rt][q] = __builtin_amdgcn_mfma_f32_16x16x32_bf16(a[rt][1], bhi, acc[rt][q], 0, 0, 0);
                acc[rt][q] = __builtin_amdgcn_mfma_f32_16x16x32_bf16(a[rt][0], blo, acc[rt][q], 0, 0, 0);
            }
        }
    }

    // ---------------- epilogue: h store (head-major bf16) + alpha reductions ----------------
    const int l15 = lane & 15, lg = lane >> 4;
    float avs[4], avd[4];
#pragma unroll
    for (int q = 0; q < 4; ++q){
        avs[q] = a_s[wid * 64 + q * 16 + l15];
        avd[q] = a_d[wid * 64 + q * 16 + l15];
    }
    float sp[4][4], dp[4][4];
#pragma unroll
    for (int rt = 0; rt < 4; ++rt){
#pragma unroll
        for (int reg = 0; reg < 4; ++reg){
            const int node = n0 + rt * 16 + lg * 4 + reg;
            float s = 0.f, d = 0.f;
            unsigned short hv[4];
#pragma unroll
            for (int q = 0; q < 4; ++q){
                const float v = acc[rt][q][reg];
                s = fmaf(v, avs[q], s); d = fmaf(v, avd[q], d);
                hv[q] = f2bf(v);
            }
            if (node < N){
#pragma unroll
                for (int q = 0; q < 4; ++q)
                    hout[((size_t)wid * N + node) * 64 + q * 16 + l15] = hv[q];
            }
            sp[rt][reg] = s; dp[rt][reg] = d;
        }
    }
#pragma unroll
    for (int off = 1; off <= 8; off <<= 1){
#pragma unroll
        for (int rt = 0; rt < 4; ++rt)
#pragma unroll
            for (int reg = 0; reg < 4; ++reg){
                sp[rt][reg] += __shfl_xor(sp[rt][reg], off, 64);
                dp[rt][reg] += __shfl_xor(dp[rt][reg], off, 64);
            }
    }
    if (l15 == 0){
#pragma unroll
        for (int rt = 0; rt < 4; ++rt)
#pragma unroll
            for (int reg = 0; reg < 4; ++reg){
                const int node = n0 + rt * 16 + lg * 4 + reg;
                if (node < N){
                    asrc[(size_t)node * 4 + wid] = sp[rt][reg];
                    adst[(size_t)node * 4 + wid] = dp[rt][reg];
                }
            }
    }
}

// ============================ CSR build (once) ============================
__global__ void deg_init_kernel(int* __restrict__ deg, int N){
    int i = blockIdx.x * blockDim.x + threadIdx.x;
    if (i < N) deg[i] = 1;                        // self-loop
}

__global__ void deg_hist_kernel(const int* __restrict__ ei, int E, int* __restrict__ deg){
    int e = blockIdx.x * blockDim.x + threadIdx.x;
    if (e < E) atomicAdd(&deg[ei[E + e]], 1);
}

__global__ __launch_bounds__(256) void part_sum_kernel(const int* __restrict__ deg,
                                                       int* __restrict__ bsum, int N)
{
    __shared__ int red[256];
    const int t = threadIdx.x;
    const int i0 = blockIdx.x * 1024 + t * 4;
    int s = 0;
    if (i0 + 3 < N){
        const int4 v = *(const int4*)&deg[i0];
        s = v.x + v.y + v.z + v.w;
    } else {
#pragma unroll
        for (int j = 0; j < 4; ++j) if (i0 + j < N) s += deg[i0 + j];
    }
    red[t] = s; __syncthreads();
    for (int off = 128; off >= 1; off >>= 1){
        if (t < off) red[t] += red[t + off];
        __syncthreads();
    }
    if (t == 0) bsum[blockIdx.x] = red[0];
}

__global__ __launch_bounds__(256) void scan_part_kernel(int* __restrict__ bsum, int nb,
                                                        int* __restrict__ row, int N)
{
    __shared__ int sh[256];
    const int t = threadIdx.x;
    const int v = (t < nb) ? bsum[t] : 0;
    sh[t] = v; __syncthreads();
    for (int off = 1; off < 256; off <<= 1){
        int u = (t >= off) ? sh[t - off] : 0;
        __syncthreads();
        sh[t] += u;
        __syncthreads();
    }
    if (t < nb) bsum[t] = sh[t] - v;              // exclusive
    if (t == nb - 1) row[N] = sh[t];              // total = E + N
}

__global__ __launch_bounds__(256) void distribute_kernel(const int* __restrict__ deg,
    const int* __restrict__ bsum, int* __restrict__ row, int* __restrict__ cursor, int N)
{
    __shared__ int ts[256];
    const int t = threadIdx.x;
    const int i0 = blockIdx.x * 1024 + t * 4;
    int d[4]; int s = 0;
#pragma unroll
    for (int j = 0; j < 4; ++j){ d[j] = (i0 + j < N) ? deg[i0 + j] : 0; s += d[j]; }
    ts[t] = s; __syncthreads();
    for (int off = 1; off < 256; off <<= 1){
        int u = (t >= off) ? ts[t - off] : 0;
        __syncthreads();
        ts[t] += u;
        __syncthreads();
    }
    int base = bsum[blockIdx.x] + ts[t] - s;      // exclusive prefix for this thread
#pragma unroll
    for (int j = 0; j < 4; ++j){
        if (i0 + j < N){ row[i0 + j] = base; cursor[i0 + j] = base; base += d[j]; }
    }
}

__global__ void scatter_kernel(const int* __restrict__ ei, int E, int N,
                               int* __restrict__ cursor, int* __restrict__ csr)
{
    int e = blockIdx.x * blockDim.x + threadIdx.x;
    if (e >= E + N) return;
    int s, d;
    if (e < E){ s = ei[e]; d = ei[E + e]; } else { s = d = e - E; }
    int pos = atomicAdd(&cursor[d], 1);
    csr[pos] = s;
}

// =========================================================================
// HEAD-SPLIT gather-aggregate: one wave per (node, head); head is the outer
// grid dim so heads run in dispatch-order phases -> gather working set per
// time window = one head's h (6.4 MB, ~L2-size) instead of 25.6 MB.
// Phase A: lane-parallel p=exp(leakyrelu(.)) -> LDS + denom butterfly
//          (asrc is 800 KB -> always L2-resident, re-gather per head is cheap).
// Phase B: 4 edges/iter, 16 lanes per edge, ushort4 (128 B/edge contiguous).
// Fused epilogue (lanes 0-15): /denom + bias + BN + ELU (+res), hi/lo out.
// =========================================================================
#define DEG_CAP 128
__global__ __launch_bounds__(256) void agg4h_kernel(
    const int* __restrict__ row, const int* __restrict__ csr,
    const float* __restrict__ asrc, const float* __restrict__ adst,
    const unsigned short* __restrict__ hh,     // [4][N][64] bf16
    const float* __restrict__ b, const float* __restrict__ g,
    const float* __restrict__ be, const float* __restrict__ mean,
    const float* __restrict__ var,
    const unsigned short* __restrict__ reshi, const unsigned short* __restrict__ reslo,
    unsigned short* __restrict__ outhi, unsigned short* __restrict__ outlo,
    int N, int gN4)
{
    __shared__ float plds[4][DEG_CAP];
    __shared__ int   slds[4][DEG_CAP];
    const int wid = threadIdx.x >> 6, lane = threadIdx.x & 63;
    const int head = blockIdx.x / gN4;
    const int node = (blockIdx.x - head * gN4) * 4 + wid;
    if (node >= N) return;
    const int beg = row[node], end = row[node + 1], deg = end - beg;
    const float adh = adst[(size_t)node * 4 + head];

    // ---- phase A: edge weights (this head) + denom ----
    float den = 0.f;
    for (int i = lane; i < deg; i += 64){
        const int s = csr[beg + i];
        float v = asrc[(size_t)s * 4 + head] + adh;
        v = v > 0.f ? v : NEG_SLOPE * v;
        const float p = __expf(v);
        den += p;
        if (i < DEG_CAP){ plds[wid][i] = p; slds[wid][i] = s; }
    }
    for (int off = 32; off >= 1; off >>= 1) den += __shfl_xor(den, off, 64);

    // ---- phase B: 4 edges per iteration; lane sub-group (16) per edge ----
    const int sub = lane >> 4, l15 = lane & 15;
    const int degc = deg < DEG_CAP ? deg : DEG_CAP;
    const size_t hbase = (size_t)head * N;
    float a0 = 0.f, a1 = 0.f, a2 = 0.f, a3 = 0.f;
    for (int i = 0; i < degc; i += 4){
        const int it = i + sub;
        const bool ok = it < degc;
        const int s_  = slds[wid][ok ? it : 0];
        const float p_ = ok ? plds[wid][it] : 0.f;
        const ushort4 hv = *(const ushort4*)&hh[(hbase + s_) * 64 + 4 * l15];
        a0 = fmaf(p_, bf2f(hv.x), a0); a1 = fmaf(p_, bf2f(hv.y), a1);
        a2 = fmaf(p_, bf2f(hv.z), a2); a3 = fmaf(p_, bf2f(hv.w), a3);
    }
    // overflow (deg > DEG_CAP): statistically never; sub-group 0 only
    if (sub == 0){
        for (int j = beg + DEG_CAP; j < end; ++j){
            const int s = csr[j];
            float v = asrc[(size_t)s * 4 + head] + adh;
            v = v > 0.f ? v : NEG_SLOPE * v;
            const float p = __expf(v);
            const ushort4 hv = *(const ushort4*)&hh[(hbase + s) * 64 + 4 * l15];
            a0 = fmaf(p, bf2f(hv.x), a0); a1 = fmaf(p, bf2f(hv.y), a1);
            a2 = fmaf(p, bf2f(hv.z), a2); a3 = fmaf(p, bf2f(hv.w), a3);
        }
    }
    // combine the 4 edge sub-groups
    a0 += __shfl_xor(a0, 16, 64); a0 += __shfl_xor(a0, 32, 64);
    a1 += __shfl_xor(a1, 16, 64); a1 += __shfl_xor(a1, 32, 64);
    a2 += __shfl_xor(a2, 16, 64); a2 += __shfl_xor(a2, 32, 64);
    a3 += __shfl_xor(a3, 16, 64); a3 += __shfl_xor(a3, 32, 64);

    // ---- fused epilogue on lanes 0..15 (4 channels each) ----
    if (lane < 16){
        const float rdi = 1.f / den;
        const int c0 = head * 64 + 4 * lane;
        const float4 bv  = *(const float4*)&b[c0];
        const float4 gv  = *(const float4*)&g[c0];
        const float4 bev = *(const float4*)&be[c0];
        const float4 mv  = *(const float4*)&mean[c0];
        const float4 vv4 = *(const float4*)&var[c0];
        float rh[4] = {0.f, 0.f, 0.f, 0.f};
        if (reshi){
            const ushort4 r1 = *(const ushort4*)&reshi[(size_t)node * 256 + c0];
            const ushort4 r2 = *(const ushort4*)&reslo[(size_t)node * 256 + c0];
            rh[0] = bf2f(r1.x) + bf2f(r2.x); rh[1] = bf2f(r1.y) + bf2f(r2.y);
            rh[2] = bf2f(r1.z) + bf2f(r2.z); rh[3] = bf2f(r1.w) + bf2f(r2.w);
        }
        const float ava[4]  = {a0, a1, a2, a3};
        const float bva[4]  = {bv.x, bv.y, bv.z, bv.w};
        const float gva[4]  = {gv.x, gv.y, gv.z, gv.w};
        const float beva[4] = {bev.x, bev.y, bev.z, bev.w};
        const float mva[4]  = {mv.x, mv.y, mv.z, mv.w};
        const float vva[4]  = {vv4.x, vv4.y, vv4.z, vv4.w};
        unsigned short hos[4], los[4];
#pragma unroll
        for (int j = 0; j < 4; ++j){
            float vvv = ava[j] * rdi + bva[j];
            vvv = (vvv - mva[j]) * (gva[j] * rsqrtf(vva[j] + BN_EPS)) + beva[j];
            vvv = vvv > 0.f ? vvv : (__expf(vvv) - 1.f);
            vvv += rh[j];
            const unsigned short hb = f2bf(vvv);
            hos[j] = hb; los[j] = f2bf(vvv - bf2f(hb));
        }
        ushort4 ho, lo4;
        ho.x = hos[0];  ho.y = hos[1];  ho.z = hos[2];  ho.w = hos[3];
        lo4.x = los[0]; lo4.y = los[1]; lo4.z = los[2]; lo4.w = los[3];
        *(ushort4*)&outhi[(size_t)node * 256 + c0] = ho;
        *(ushort4*)&outlo[(size_t)node * 256 + c0] = lo4;
    }
}

// ------------------------- layer 2 (heads=1, C=1) -------------------------
__global__ __launch_bounds__(256) void gemm2_kernel(
    const unsigned short* __restrict__ xhi, const unsigned short* __restrict__ xlo,
    const float* __restrict__ W2, float* __restrict__ h2, int N)
{
    const int wid = threadIdx.x >> 6, lane = threadIdx.x & 63;
    const int n = blockIdx.x * 4 + wid;
    if (n >= N) return;
    float sum = 0.f;
#pragma unroll
    for (int i = 0; i < 4; ++i){
        const int c = i * 64 + lane;
        sum += (bf2f(xhi[(size_t)n * 256 + c]) + bf2f(xlo[(size_t)n * 256 + c])) * W2[c];
    }
    for (int off = 32; off >= 1; off >>= 1) sum += __shfl_xor(sum, off, 64);
    if (lane == 0) h2[n] = sum;
}

__global__ void agg2_kernel(const int* __restrict__ row, const int* __restrict__ csr,
                            const float* __restrict__ h2,
                            const float* __restrict__ as2, const float* __restrict__ ad2,
                            const float* __restrict__ b2, float* __restrict__ out, int N)
{
    const int n = blockIdx.x * blockDim.x + threadIdx.x;
    if (n >= N) return;
    const float A_s = as2[0];
    const float hd  = h2[n] * ad2[0];
    const int beg = row[n], end = row[n + 1];
    float den = 0.f, acc = 0.f;
    for (int i = beg; i < end; ++i){
        const float hv = h2[csr[i]];
        float a = fmaf(A_s, hv, hd);
        a = a > 0.f ? a : NEG_SLOPE * a;
        const float p = __expf(a);
        den += p; acc = fmaf(p, hv, acc);
    }
    out[n] = acc / den + b2[0];
}

// =========================================================================
extern "C" void kernel_launch(void* const* d_in, const int* in_sizes, int n_in,
                              void* d_out, int out_size, void* d_ws, size_t ws_size,
                              hipStream_t stream)
{
    const float* x   = (const float*)d_in[0];
    const int*   ei  = (const int*)  d_in[1];
    const float* W0  = (const float*)d_in[2];
    const float* as0 = (const float*)d_in[3];
    const float* ad0 = (const float*)d_in[4];
    const float* b0  = (const float*)d_in[5];
    const float* W1  = (const float*)d_in[6];
    const float* as1 = (const float*)d_in[7];
    const float* ad1 = (const float*)d_in[8];
    const float* b1  = (const float*)d_in[9];
    const float* W2  = (const float*)d_in[10];
    const float* as2 = (const float*)d_in[11];
    const float* ad2 = (const float*)d_in[12];
    const float* b2  = (const float*)d_in[13];
    const float* g0  = (const float*)d_in[14];
    const float* be0 = (const float*)d_in[15];
    const float* m0  = (const float*)d_in[16];
    const float* v0  = (const float*)d_in[17];
    const float* g1  = (const float*)d_in[18];
    const float* be1 = (const float*)d_in[19];
    const float* m1  = (const float*)d_in[20];
    const float* v1  = (const float*)d_in[21];

    const int N = in_sizes[0] / 128;
    const int E = in_sizes[1] / 2;
    const int EN = E + N;

    // ---- workspace layout (hi/lo activation planes; P1hi aliases X0) ----
    char* w = (char*)d_ws;
    unsigned short* H    = (unsigned short*)w;  w += (size_t)N * 256 * 2;  // h bf16 [4][N][64]
    unsigned short* X0hi = (unsigned short*)w;                              // N*128 bf16
    unsigned short* X0lo = X0hi + (size_t)N * 128;
    unsigned short* P1hi = X0hi;                // alias: X0 dead after layer-0 GEMM
    w += (size_t)N * 256 * 2;
    unsigned short* P0hi = (unsigned short*)w;  w += (size_t)N * 256 * 2;
    unsigned short* P0lo = (unsigned short*)w;  w += (size_t)N * 256 * 2;
    unsigned short* P1lo = (unsigned short*)w;  w += (size_t)N * 256 * 2;
    float*    asrc   = (float*)w;   w += (size_t)N * 4 * 4;
    float*    adst   = (float*)w;   w += (size_t)N * 4 * 4;
    int*      deg    = (int*)w;     w += (size_t)N * 4;
    int*      cursor = (int*)w;     w += (size_t)N * 4;
    int*      csr    = (int*)w;     w += (size_t)EN * 4;
    float*    h2     = (float*)w;   w += (size_t)N * 4;
    int*      bsum   = (int*)w;     w += 1024;
    unsigned short* Wb0hi = (unsigned short*)w; w += (size_t)128 * 256 * 2;
    unsigned short* Wb0lo = (unsigned short*)w; w += (size_t)128 * 256 * 2;
    unsigned short* Wb1hi = (unsigned short*)w; w += (size_t)256 * 256 * 2;
    unsigned short* Wb1lo = (unsigned short*)w; w += (size_t)256 * 256 * 2;
    int*      rowp   = (int*)w;     w += (size_t)(N + 1) * 4;   // last (odd size)

    const int gN64  = (N + 63) / 64;
    const int gN4   = (N + 3) / 4;
    const int gNt   = (N + 255) / 256;
    const int gE    = (E + 255) / 256;
    const int gEN   = (EN + 255) / 256;
    const int nb    = (N + 1023) / 1024;

    // ---------------- one-time prep: hi/lo planes, W repack, CSR ----------------
    conv_hilo_kernel<<<(N * 128 / 4 + 255) / 256, 256, 0, stream>>>(x, X0hi, X0lo, N * 128 / 4);
    repack_w_kernel<<<128, 256, 0, stream>>>(W0, Wb0hi, Wb0lo);
    repack_w_kernel<<<256, 256, 0, stream>>>(W1, Wb1hi, Wb1lo);
    deg_init_kernel<<<gNt, 256, 0, stream>>>(deg, N);
    deg_hist_kernel<<<gE, 256, 0, stream>>>(ei, E, deg);
    part_sum_kernel<<<nb, 256, 0, stream>>>(deg, bsum, N);
    scan_part_kernel<<<1, 256, 0, stream>>>(bsum, nb, rowp, N);
    distribute_kernel<<<nb, 256, 0, stream>>>(deg, bsum, rowp, cursor, N);
    scatter_kernel<<<gEN, 256, 0, stream>>>(ei, E, N, cursor, csr);

    // ---------------- layer 0 ----------------
    mfma_gemm_alpha<128><<<gN64, 256, 0, stream>>>(X0hi, X0lo, Wb0hi, Wb0lo,
                                                   as0, ad0, H, asrc, adst, N);
    agg4h_kernel<<<gN4 * 4, 256, 0, stream>>>(rowp, csr, asrc, adst, H,
                                              b0, g0, be0, m0, v0,
                                              nullptr, nullptr, P0hi, P0lo, N, gN4);

    // ---------------- layer 1 ----------------
    mfma_gemm_alpha<256><<<gN64, 256, 0, stream>>>(P0hi, P0lo, Wb1hi, Wb1lo,
                                                   as1, ad1, H, asrc, adst, N);
    agg4h_kernel<<<gN4 * 4, 256, 0, stream>>>(rowp, csr, asrc, adst, H,
                                              b1, g1, be1, m1, v1,
                                              P0hi, P0lo, P1hi, P1lo, N, gN4);

    // ---------------- layer 2 ----------------
    gemm2_kernel<<<gN4, 256, 0, stream>>>(P1hi, P1lo, W2, h2, N);
    agg2_kernel<<<gNt, 256, 0, stream>>>(rowp, csr, h2, as2, ad2, b2, (float*)d_out, N);
}

// Round 9
// 345.997 us; speedup vs baseline: 1.3239x; 1.3239x over previous
//
#include <hip/hip_runtime.h>
#include <math.h>

#define NEG_SLOPE 0.2f
#define BN_EPS 1e-5f

typedef __attribute__((ext_vector_type(8))) short bf16x8;
typedef __attribute__((ext_vector_type(4))) float f32x4;

static __device__ __forceinline__ unsigned short f2bf(float f){
    unsigned u = __float_as_uint(f);
    u += 0x7FFFu + ((u >> 16) & 1u);          // round-to-nearest-even
    return (unsigned short)(u >> 16);
}
static __device__ __forceinline__ float bf2f(unsigned short v){
    return __uint_as_float((unsigned)v << 16);
}

// async global->LDS, 16B/lane; LDS dest wave-uniform base + lane*16
static __device__ __forceinline__ void gload_lds16(const void* g, void* l){
    __builtin_amdgcn_global_load_lds(
        (const __attribute__((address_space(1))) void*)g,
        (__attribute__((address_space(3))) void*)l, 16, 0, 0);
}

// ---- fp32 -> (hi, lo) bf16 planes, elementwise ----
__global__ void conv_hilo_kernel(const float* __restrict__ x,
                                 unsigned short* __restrict__ hi,
                                 unsigned short* __restrict__ lo, int n4)
{
    int i = blockIdx.x * 256 + threadIdx.x;
    if (i >= n4) return;
    const float4 v = ((const float4*)x)[i];
    ushort4 h4, l4;
    h4.x = f2bf(v.x); l4.x = f2bf(v.x - bf2f(h4.x));
    h4.y = f2bf(v.y); l4.y = f2bf(v.y - bf2f(h4.y));
    h4.z = f2bf(v.z); l4.z = f2bf(v.z - bf2f(h4.z));
    h4.w = f2bf(v.w); l4.w = f2bf(v.w - bf2f(h4.w));
    ((ushort4*)hi)[i] = h4; ((ushort4*)lo)[i] = l4;
}

// ---- W [K][256] fp32 -> MFMA B-fragment layout, hi/lo bf16 planes ----
// out index o = (((kt*16+ct)*64+lane)*8+j);  k = kt*32+8*(lane>>4)+j, col = ct*16+(lane&15)
__global__ void repack_w_kernel(const float* __restrict__ W,
                                unsigned short* __restrict__ wbhi,
                                unsigned short* __restrict__ wblo)
{
    const int o = blockIdx.x * 256 + threadIdx.x;
    const int j = o & 7, ln = (o >> 3) & 63, ct = (o >> 9) & 15, kt = o >> 13;
    const int k = kt * 32 + 8 * (ln >> 4) + j;
    const int col = ct * 16 + (ln & 15);
    const float v = W[k * 256 + col];
    const unsigned short hb = f2bf(v);
    wbhi[o] = hb; wblo[o] = f2bf(v - bf2f(hb));
}

// =========================================================================
// MFMA GEMM h = x @ W ([N,K]@[K,256]) + per-head alpha reductions.
// Block = 256 thr = 4 waves = 64-node tile. Wave w owns col-tiles w*4..w*4+3
// (= head w). 3-pass hi/lo MFMA into shared fp32 acc. K-step = 32.
// C/D mapping (verified): col=lane&15, row=(lane>>4)*4+reg.
// =========================================================================
template<int K>
__global__ __launch_bounds__(256) void mfma_gemm_alpha(
    const unsigned short* __restrict__ xhi, const unsigned short* __restrict__ xlo,
    const unsigned short* __restrict__ wbhi, const unsigned short* __restrict__ wblo,
    const float* __restrict__ a_s, const float* __restrict__ a_d,
    unsigned short* __restrict__ hout,
    float* __restrict__ asrc, float* __restrict__ adst, int N)
{
    __shared__ unsigned short xa[8][512];     // [rt*2+plane][lane*8] A-frags
    __shared__ unsigned short wb[32][512];    // [ct*2+plane][lane*8] B-frags
    const int t = threadIdx.x, lane = t & 63, wid = t >> 6;
    const int n0 = blockIdx.x * 64;

    f32x4 acc[4][4];
#pragma unroll
    for (int rt = 0; rt < 4; ++rt)
#pragma unroll
        for (int q = 0; q < 4; ++q) acc[rt][q] = (f32x4){0.f, 0.f, 0.f, 0.f};

    for (int kt = 0; kt < K / 32; ++kt){
        __syncthreads();                      // previous iteration reads done
        // stage A-frags: 8 x 1KB, wave wid issues 2
#pragma unroll
        for (int ii = 0; ii < 2; ++ii){
            const int i = wid * 2 + ii;
            const int rt = i >> 1, plane = i & 1;
            int node = n0 + rt * 16 + (lane & 15);
            if (node > N - 1) node = N - 1;   // clamp; results discarded later
            const unsigned short* src = (plane ? xlo : xhi)
                + (size_t)node * K + kt * 32 + 8 * (lane >> 4);
            gload_lds16(src, &xa[i][0]);
        }
        // stage B-frags: 32 x 1KB, wave wid issues 8 (linear, coalesced)
#pragma unroll
        for (int ii = 0; ii < 8; ++ii){
            const int i = wid * 8 + ii;
            const int ct = i >> 1, plane = i & 1;
            const unsigned short* base = plane ? wblo : wbhi;
            gload_lds16(base + ((size_t)(kt * 16 + ct) * 64 + lane) * 8, &wb[i][0]);
        }
        __syncthreads();                      // drains vmcnt (incl. lds loads)

        bf16x8 a[4][2];
#pragma unroll
        for (int rt = 0; rt < 4; ++rt)
#pragma unroll
            for (int pl = 0; pl < 2; ++pl)
                a[rt][pl] = *(const bf16x8*)&xa[rt * 2 + pl][lane * 8];

#pragma unroll
        for (int q = 0; q < 4; ++q){
            const int cti = wid * 4 + q;
            const bf16x8 bhi = *(const bf16x8*)&wb[cti * 2 + 0][lane * 8];
            const bf16x8 blo = *(const bf16x8*)&wb[cti * 2 + 1][lane * 8];
#pragma unroll
            for (int rt = 0; rt < 4; ++rt){
                acc[rt][q] = __builtin_amdgcn_mfma_f32_16x16x32_bf16(a[rt][0], bhi, acc[rt][q], 0, 0, 0);
                acc[rt][q] = __builtin_amdgcn_mfma_f32_16x16x32_bf16(a[rt][1], bhi, acc[rt][q], 0, 0, 0);
                acc[rt][q] = __builtin_amdgcn_mfma_f32_16x16x32_bf16(a[rt][0], blo, acc[rt][q], 0, 0, 0);
            }
        }
    }

    // ---------------- epilogue: h store (bf16 [node][256]) + alpha reductions ----------------
    const int l15 = lane & 15, lg = lane >> 4;
    float avs[4], avd[4];
#pragma unroll
    for (int q = 0; q < 4; ++q){
        avs[q] = a_s[wid * 64 + q * 16 + l15];
        avd[q] = a_d[wid * 64 + q * 16 + l15];
    }
    float sp[4][4], dp[4][4];
#pragma unroll
    for (int rt = 0; rt < 4; ++rt){
#pragma unroll
        for (int reg = 0; reg < 4; ++reg){
            const int node = n0 + rt * 16 + lg * 4 + reg;
            float s = 0.f, d = 0.f;
            unsigned short hv[4];
#pragma unroll
            for (int q = 0; q < 4; ++q){
                const float v = acc[rt][q][reg];
                s = fmaf(v, avs[q], s); d = fmaf(v, avd[q], d);
                hv[q] = f2bf(v);
            }
            if (node < N){
#pragma unroll
                for (int q = 0; q < 4; ++q)
                    hout[(size_t)node * 256 + (wid * 4 + q) * 16 + l15] = hv[q];
            }
            sp[rt][reg] = s; dp[rt][reg] = d;
        }
    }
#pragma unroll
    for (int off = 1; off <= 8; off <<= 1){
#pragma unroll
        for (int rt = 0; rt < 4; ++rt)
#pragma unroll
            for (int reg = 0; reg < 4; ++reg){
                sp[rt][reg] += __shfl_xor(sp[rt][reg], off, 64);
                dp[rt][reg] += __shfl_xor(dp[rt][reg], off, 64);
            }
    }
    if (l15 == 0){
#pragma unroll
        for (int rt = 0; rt < 4; ++rt)
#pragma unroll
            for (int reg = 0; reg < 4; ++reg){
                const int node = n0 + rt * 16 + lg * 4 + reg;
                if (node < N){
                    asrc[(size_t)node * 4 + wid] = sp[rt][reg];
                    adst[(size_t)node * 4 + wid] = dp[rt][reg];
                }
            }
    }
}

// ============================ CSR build (once) ============================
__global__ void deg_init_kernel(int* __restrict__ deg, int N){
    int i = blockIdx.x * blockDim.x + threadIdx.x;
    if (i < N) deg[i] = 1;                        // self-loop
}

__global__ void deg_hist_kernel(const int* __restrict__ ei, int E, int* __restrict__ deg){
    int e = blockIdx.x * blockDim.x + threadIdx.x;
    if (e < E) atomicAdd(&deg[ei[E + e]], 1);
}

__global__ __launch_bounds__(256) void part_sum_kernel(const int* __restrict__ deg,
                                                       int* __restrict__ bsum, int N)
{
    __shared__ int red[256];
    const int t = threadIdx.x;
    const int i0 = blockIdx.x * 1024 + t * 4;
    int s = 0;
    if (i0 + 3 < N){
        const int4 v = *(const int4*)&deg[i0];
        s = v.x + v.y + v.z + v.w;
    } else {
#pragma unroll
        for (int j = 0; j < 4; ++j) if (i0 + j < N) s += deg[i0 + j];
    }
    red[t] = s; __syncthreads();
    for (int off = 128; off >= 1; off >>= 1){
        if (t < off) red[t] += red[t + off];
        __syncthreads();
    }
    if (t == 0) bsum[blockIdx.x] = red[0];
}

__global__ __launch_bounds__(256) void scan_part_kernel(int* __restrict__ bsum, int nb,
                                                        int* __restrict__ row, int N)
{
    __shared__ int sh[256];
    const int t = threadIdx.x;
    const int v = (t < nb) ? bsum[t] : 0;
    sh[t] = v; __syncthreads();
    for (int off = 1; off < 256; off <<= 1){
        int u = (t >= off) ? sh[t - off] : 0;
        __syncthreads();
        sh[t] += u;
        __syncthreads();
    }
    if (t < nb) bsum[t] = sh[t] - v;              // exclusive
    if (t == nb - 1) row[N] = sh[t];              // total = E + N
}

__global__ __launch_bounds__(256) void distribute_kernel(const int* __restrict__ deg,
    const int* __restrict__ bsum, int* __restrict__ row, int* __restrict__ cursor, int N)
{
    __shared__ int ts[256];
    const int t = threadIdx.x;
    const int i0 = blockIdx.x * 1024 + t * 4;
    int d[4]; int s = 0;
#pragma unroll
    for (int j = 0; j < 4; ++j){ d[j] = (i0 + j < N) ? deg[i0 + j] : 0; s += d[j]; }
    ts[t] = s; __syncthreads();
    for (int off = 1; off < 256; off <<= 1){
        int u = (t >= off) ? ts[t - off] : 0;
        __syncthreads();
        ts[t] += u;
        __syncthreads();
    }
    int base = bsum[blockIdx.x] + ts[t] - s;      // exclusive prefix for this thread
#pragma unroll
    for (int j = 0; j < 4; ++j){
        if (i0 + j < N){ row[i0 + j] = base; cursor[i0 + j] = base; base += d[j]; }
    }
}

__global__ void scatter_kernel(const int* __restrict__ ei, int E, int N,
                               int* __restrict__ cursor, int* __restrict__ csr)
{
    int e = blockIdx.x * blockDim.x + threadIdx.x;
    if (e >= E + N) return;
    int s, d;
    if (e < E){ s = ei[e]; d = ei[E + e]; } else { s = d = e - E; }
    int pos = atomicAdd(&cursor[d], 1);
    csr[pos] = s;
}

// =========================================================================
// Gather-aggregate per destination node: one wave per node, 4 waves/block.
// h [node][256] bf16; lane owns (head = lane>>4, channels 4*lane..4*lane+3).
// Phase A: lane-parallel p = exp(leakyrelu(e)) -> LDS (byte offsets s<<9,
//          4 zero-pad slots) + denom butterfly.
// Phase B: distance-2 software-pipelined gather (2 rows in flight in regs),
//          branch-free via pad slots. Fused /denom+bias+BN+ELU(+res) epilogue.
// =========================================================================
#define DEG_CAP 128
__global__ __launch_bounds__(256) void agg4_kernel(
    const int* __restrict__ row, const int* __restrict__ csr,
    const float* __restrict__ asrc, const float* __restrict__ adst,
    const unsigned short* __restrict__ h,
    const float* __restrict__ b, const float* __restrict__ g,
    const float* __restrict__ be, const float* __restrict__ mean,
    const float* __restrict__ var,
    const unsigned short* __restrict__ reshi, const unsigned short* __restrict__ reslo,
    unsigned short* __restrict__ outhi, unsigned short* __restrict__ outlo, int N)
{
    __shared__ float plds[4][(DEG_CAP + 4) * 4];
    __shared__ int   slds[4][DEG_CAP + 4];
    const int wid = threadIdx.x >> 6, lane = threadIdx.x & 63;
    const int node = blockIdx.x * 4 + wid;
    if (node >= N) return;
    const int beg = row[node], end = row[node + 1], deg = end - beg;
    const int degc = deg < DEG_CAP ? deg : DEG_CAP;
    const int head = lane >> 4;

    const float4 ad = *(const float4*)&adst[(size_t)node * 4];

    // ---- phase A: edge weights + denom (lane-parallel) ----
    float d0 = 0.f, d1 = 0.f, d2 = 0.f, d3 = 0.f;
    for (int i = lane; i < deg; i += 64){
        const int s = csr[beg + i];
        const float4 as = *(const float4*)&asrc[(size_t)s * 4];
        float v0 = as.x + ad.x, v1 = as.y + ad.y, v2 = as.z + ad.z, v3 = as.w + ad.w;
        v0 = v0 > 0.f ? v0 : NEG_SLOPE * v0;
        v1 = v1 > 0.f ? v1 : NEG_SLOPE * v1;
        v2 = v2 > 0.f ? v2 : NEG_SLOPE * v2;
        v3 = v3 > 0.f ? v3 : NEG_SLOPE * v3;
        const float p0 = __expf(v0), p1 = __expf(v1);
        const float p2 = __expf(v2), p3 = __expf(v3);
        d0 += p0; d1 += p1; d2 += p2; d3 += p3;
        if (i < DEG_CAP){
            *(float4*)&plds[wid][i * 4] = make_float4(p0, p1, p2, p3);
            slds[wid][i] = s << 9;               // byte offset of h row
        }
    }
    if (lane < 4){                               // zero-pad pipeline slots
        const int slot = degc + lane;
        *(float4*)&plds[wid][slot * 4] = make_float4(0.f, 0.f, 0.f, 0.f);
        slds[wid][slot] = 0;
    }
    for (int off = 32; off >= 1; off >>= 1){
        d0 += __shfl_xor(d0, off, 64); d1 += __shfl_xor(d1, off, 64);
        d2 += __shfl_xor(d2, off, 64); d3 += __shfl_xor(d3, off, 64);
    }

    // ---- phase B: pipelined weighted gather-accumulate ----
    float a0 = 0.f, a1 = 0.f, a2 = 0.f, a3 = 0.f;
    {
        const char* hb = (const char*)h + lane * 8;
        const float* pb = &plds[wid][0];
        const int* sb = &slds[wid][0];
        ushort4 hA = *(const ushort4*)(hb + sb[0]);
        ushort4 hB = *(const ushort4*)(hb + sb[1]);
        for (int i = 0; i < degc; i += 2){
            const ushort4 hC = *(const ushort4*)(hb + sb[i + 2]);
            const ushort4 hD = *(const ushort4*)(hb + sb[i + 3]);
            const float pA = pb[i * 4 + head];
            const float pB = pb[(i + 1) * 4 + head];
            a0 = fmaf(pA, bf2f(hA.x), a0); a1 = fmaf(pA, bf2f(hA.y), a1);
            a2 = fmaf(pA, bf2f(hA.z), a2); a3 = fmaf(pA, bf2f(hA.w), a3);
            a0 = fmaf(pB, bf2f(hB.x), a0); a1 = fmaf(pB, bf2f(hB.y), a1);
            a2 = fmaf(pB, bf2f(hB.z), a2); a3 = fmaf(pB, bf2f(hB.w), a3);
            hA = hC; hB = hD;
        }
    }

    // overflow path (deg > DEG_CAP): recompute p inline (statistically never)
    for (int jj = beg + DEG_CAP; jj < end; ++jj){
        const int s = csr[jj];
        const float4 as = *(const float4*)&asrc[(size_t)s * 4];
        float e0 = as.x + ad.x, e1 = as.y + ad.y, e2 = as.z + ad.z, e3 = as.w + ad.w;
        float eh = (head == 0) ? e0 : (head == 1) ? e1 : (head == 2) ? e2 : e3;
        eh = eh > 0.f ? eh : NEG_SLOPE * eh;
        const float p = __expf(eh);
        const ushort4 hv = *(const ushort4*)&h[(size_t)s * 256 + lane * 4];
        a0 = fmaf(p, bf2f(hv.x), a0); a1 = fmaf(p, bf2f(hv.y), a1);
        a2 = fmaf(p, bf2f(hv.z), a2); a3 = fmaf(p, bf2f(hv.w), a3);
    }

    // ---- fused epilogue ----
    const int l15 = lane & 15;
    const float dsel = (head == 0) ? d0 : (head == 1) ? d1 : (head == 2) ? d2 : d3;
    const float rdi = 1.f / dsel;
    const int c0 = head * 64 + 4 * l15;
    const float4 bv  = *(const float4*)&b[c0];
    const float4 gv  = *(const float4*)&g[c0];
    const float4 bev = *(const float4*)&be[c0];
    const float4 mv  = *(const float4*)&mean[c0];
    const float4 vv4 = *(const float4*)&var[c0];
    const float ava[4]  = {a0, a1, a2, a3};
    const float bva[4]  = {bv.x, bv.y, bv.z, bv.w};
    const float gva[4]  = {gv.x, gv.y, gv.z, gv.w};
    const float beva[4] = {bev.x, bev.y, bev.z, bev.w};
    const float mva[4]  = {mv.x, mv.y, mv.z, mv.w};
    const float vva[4]  = {vv4.x, vv4.y, vv4.z, vv4.w};
    float rh[4] = {0.f, 0.f, 0.f, 0.f};
    if (reshi){
        const ushort4 r1 = *(const ushort4*)&reshi[(size_t)node * 256 + c0];
        const ushort4 r2 = *(const ushort4*)&reslo[(size_t)node * 256 + c0];
        rh[0] = bf2f(r1.x) + bf2f(r2.x); rh[1] = bf2f(r1.y) + bf2f(r2.y);
        rh[2] = bf2f(r1.z) + bf2f(r2.z); rh[3] = bf2f(r1.w) + bf2f(r2.w);
    }
    unsigned short hos[4], los[4];
#pragma unroll
    for (int j = 0; j < 4; ++j){
        float vvv = ava[j] * rdi + bva[j];
        vvv = (vvv - mva[j]) * (gva[j] * rsqrtf(vva[j] + BN_EPS)) + beva[j];
        vvv = vvv > 0.f ? vvv : (__expf(vvv) - 1.f);
        vvv += rh[j];
        const unsigned short hb2 = f2bf(vvv);
        hos[j] = hb2; los[j] = f2bf(vvv - bf2f(hb2));
    }
    ushort4 ho, lo4;
    ho.x = hos[0];  ho.y = hos[1];  ho.z = hos[2];  ho.w = hos[3];
    lo4.x = los[0]; lo4.y = los[1]; lo4.z = los[2]; lo4.w = los[3];
    *(ushort4*)&outhi[(size_t)node * 256 + c0] = ho;
    *(ushort4*)&outlo[(size_t)node * 256 + c0] = lo4;
}

// ------------------------- layer 2 (heads=1, C=1) -------------------------
__global__ __launch_bounds__(256) void gemm2_kernel(
    const unsigned short* __restrict__ xhi, const unsigned short* __restrict__ xlo,
    const float* __restrict__ W2, float* __restrict__ h2, int N)
{
    const int wid = threadIdx.x >> 6, lane = threadIdx.x & 63;
    const int n = blockIdx.x * 4 + wid;
    if (n >= N) return;
    float sum = 0.f;
#pragma unroll
    for (int i = 0; i < 4; ++i){
        const int c = i * 64 + lane;
        sum += (bf2f(xhi[(size_t)n * 256 + c]) + bf2f(xlo[(size_t)n * 256 + c])) * W2[c];
    }
    for (int off = 32; off >= 1; off >>= 1) sum += __shfl_xor(sum, off, 64);
    if (lane == 0) h2[n] = sum;
}

__global__ void agg2_kernel(const int* __restrict__ row, const int* __restrict__ csr,
                            const float* __restrict__ h2,
                            const float* __restrict__ as2, const float* __restrict__ ad2,
                            const float* __restrict__ b2, float* __restrict__ out, int N)
{
    const int n = blockIdx.x * blockDim.x + threadIdx.x;
    if (n >= N) return;
    const float A_s = as2[0];
    const float hd  = h2[n] * ad2[0];
    const int beg = row[n], end = row[n + 1];
    float den = 0.f, acc = 0.f;
    for (int i = beg; i < end; ++i){
        const float hv = h2[csr[i]];
        float a = fmaf(A_s, hv, hd);
        a = a > 0.f ? a : NEG_SLOPE * a;
        const float p = __expf(a);
        den += p; acc = fmaf(p, hv, acc);
    }
    out[n] = acc / den + b2[0];
}

// =========================================================================
extern "C" void kernel_launch(void* const* d_in, const int* in_sizes, int n_in,
                              void* d_out, int out_size, void* d_ws, size_t ws_size,
                              hipStream_t stream)
{
    const float* x   = (const float*)d_in[0];
    const int*   ei  = (const int*)  d_in[1];
    const float* W0  = (const float*)d_in[2];
    const float* as0 = (const float*)d_in[3];
    const float* ad0 = (const float*)d_in[4];
    const float* b0  = (const float*)d_in[5];
    const float* W1  = (const float*)d_in[6];
    const float* as1 = (const float*)d_in[7];
    const float* ad1 = (const float*)d_in[8];
    const float* b1  = (const float*)d_in[9];
    const float* W2  = (const float*)d_in[10];
    const float* as2 = (const float*)d_in[11];
    const float* ad2 = (const float*)d_in[12];
    const float* b2  = (const float*)d_in[13];
    const float* g0  = (const float*)d_in[14];
    const float* be0 = (const float*)d_in[15];
    const float* m0  = (const float*)d_in[16];
    const float* v0  = (const float*)d_in[17];
    const float* g1  = (const float*)d_in[18];
    const float* be1 = (const float*)d_in[19];
    const float* m1  = (const float*)d_in[20];
    const float* v1  = (const float*)d_in[21];

    const int N = in_sizes[0] / 128;
    const int E = in_sizes[1] / 2;
    const int EN = E + N;

    // ---- workspace layout (hi/lo activation planes; P1hi aliases X0) ----
    char* w = (char*)d_ws;
    unsigned short* H    = (unsigned short*)w;  w += (size_t)N * 256 * 2;  // h bf16 [N][256]
    unsigned short* X0hi = (unsigned short*)w;                              // N*128 bf16
    unsigned short* X0lo = X0hi + (size_t)N * 128;
    unsigned short* P1hi = X0hi;                // alias: X0 dead after layer-0 GEMM
    w += (size_t)N * 256 * 2;
    unsigned short* P0hi = (unsigned short*)w;  w += (size_t)N * 256 * 2;
    unsigned short* P0lo = (unsigned short*)w;  w += (size_t)N * 256 * 2;
    unsigned short* P1lo = (unsigned short*)w;  w += (size_t)N * 256 * 2;
    float*    asrc   = (float*)w;   w += (size_t)N * 4 * 4;
    float*    adst   = (float*)w;   w += (size_t)N * 4 * 4;
    int*      deg    = (int*)w;     w += (size_t)N * 4;
    int*      cursor = (int*)w;     w += (size_t)N * 4;
    int*      csr    = (int*)w;     w += (size_t)EN * 4;
    float*    h2     = (float*)w;   w += (size_t)N * 4;
    int*      bsum   = (int*)w;     w += 1024;
    unsigned short* Wb0hi = (unsigned short*)w; w += (size_t)128 * 256 * 2;
    unsigned short* Wb0lo = (unsigned short*)w; w += (size_t)128 * 256 * 2;
    unsigned short* Wb1hi = (unsigned short*)w; w += (size_t)256 * 256 * 2;
    unsigned short* Wb1lo = (unsigned short*)w; w += (size_t)256 * 256 * 2;
    int*      rowp   = (int*)w;     w += (size_t)(N + 1) * 4;   // last (odd size)

    const int gN64  = (N + 63) / 64;
    const int gN4   = (N + 3) / 4;
    const int gNt   = (N + 255) / 256;
    const int gE    = (E + 255) / 256;
    const int gEN   = (EN + 255) / 256;
    const int nb    = (N + 1023) / 1024;

    // ---------------- one-time prep: hi/lo planes, W repack, CSR ----------------
    conv_hilo_kernel<<<(N * 128 / 4 + 255) / 256, 256, 0, stream>>>(x, X0hi, X0lo, N * 128 / 4);
    repack_w_kernel<<<128, 256, 0, stream>>>(W0, Wb0hi, Wb0lo);
    repack_w_kernel<<<256, 256, 0, stream>>>(W1, Wb1hi, Wb1lo);
    deg_init_kernel<<<gNt, 256, 0, stream>>>(deg, N);
    deg_hist_kernel<<<gE, 256, 0, stream>>>(ei, E, deg);
    part_sum_kernel<<<nb, 256, 0, stream>>>(deg, bsum, N);
    scan_part_kernel<<<1, 256, 0, stream>>>(bsum, nb, rowp, N);
    distribute_kernel<<<nb, 256, 0, stream>>>(deg, bsum, rowp, cursor, N);
    scatter_kernel<<<gEN, 256, 0, stream>>>(ei, E, N, cursor, csr);

    // ---------------- layer 0 ----------------
    mfma_gemm_alpha<128><<<gN64, 256, 0, stream>>>(X0hi, X0lo, Wb0hi, Wb0lo,
                                                   as0, ad0, H, asrc, adst, N);
    agg4_kernel<<<gN4, 256, 0, stream>>>(rowp, csr, asrc, adst, H,
                                         b0, g0, be0, m0, v0,
                                         nullptr, nullptr, P0hi, P0lo, N);

    // ---------------- layer 1 ----------------
    mfma_gemm_alpha<256><<<gN64, 256, 0, stream>>>(P0hi, P0lo, Wb1hi, Wb1lo,
                                                   as1, ad1, H, asrc, adst, N);
    agg4_kernel<<<gN4, 256, 0, stream>>>(rowp, csr, asrc, adst, H,
                                         b1, g1, be1, m1, v1,
                                         P0hi, P0lo, P1hi, P1lo, N);

    // ---------------- layer 2 ----------------
    gemm2_kernel<<<gN4, 256, 0, stream>>>(P1hi, P1lo, W2, h2, N);
    agg2_kernel<<<gNt, 256, 0, stream>>>(rowp, csr, h2, as2, ad2, b2, (float*)d_out, N);
}

// Round 10
// 331.546 us; speedup vs baseline: 1.3816x; 1.0436x over previous
//
#include <hip/hip_runtime.h>
#include <math.h>

#define NEG_SLOPE 0.2f
#define BN_EPS 1e-5f

typedef __attribute__((ext_vector_type(8))) short bf16x8;
typedef __attribute__((ext_vector_type(4))) float f32x4;

static __device__ __forceinline__ unsigned short f2bf(float f){
    unsigned u = __float_as_uint(f);
    u += 0x7FFFu + ((u >> 16) & 1u);          // round-to-nearest-even
    return (unsigned short)(u >> 16);
}
static __device__ __forceinline__ float bf2f(unsigned short v){
    return __uint_as_float((unsigned)v << 16);
}

// async global->LDS, 16B/lane; LDS dest wave-uniform base + lane*16
static __device__ __forceinline__ void gload_lds16(const void* g, void* l){
    __builtin_amdgcn_global_load_lds(
        (const __attribute__((address_space(1))) void*)g,
        (__attribute__((address_space(3))) void*)l, 16, 0, 0);
}

// ---- fused prep: repack W0, W1 to MFMA B-frag hi/lo planes + deg_init ----
// B-frag repack: out o = (((kt*16+ct)*64+lane)*8+j); k = kt*32+8*(lane>>4)+j,
// col = ct*16+(lane&15)
static __device__ __forceinline__ void repack_one(const float* __restrict__ W,
    unsigned short* __restrict__ whi, unsigned short* __restrict__ wlo, int o)
{
    const int j = o & 7, ln = (o >> 3) & 63, ct = (o >> 9) & 15, kt = o >> 13;
    const int k = kt * 32 + 8 * (ln >> 4) + j;
    const int col = ct * 16 + (ln & 15);
    const float v = W[k * 256 + col];
    const unsigned short hb = f2bf(v);
    whi[o] = hb; wlo[o] = f2bf(v - bf2f(hb));
}

__global__ void prep_kernel(const float* __restrict__ W0,
    unsigned short* __restrict__ w0hi, unsigned short* __restrict__ w0lo,
    const float* __restrict__ W1,
    unsigned short* __restrict__ w1hi, unsigned short* __restrict__ w1lo,
    int* __restrict__ deg, int N)
{
    const int bid = blockIdx.x, t = threadIdx.x;
    if (bid < 128){
        repack_one(W0, w0hi, w0lo, bid * 256 + t);
    } else if (bid < 384){
        repack_one(W1, w1hi, w1lo, (bid - 128) * 256 + t);
    } else {
        const int i = (bid - 384) * 256 + t;
        if (i < N) deg[i] = 1;                // self-loop
    }
}

// =========================================================================
// MFMA GEMM h = x @ W ([N,K]@[K,256]) + per-head alpha reductions.
// x is fp32; hi/lo bf16 split done IN-REGISTER after LDS staging.
// Block = 256 thr = 4 waves = 64-node tile. Wave w owns col-tiles w*4..w*4+3
// (= head w). 3-pass hi/lo MFMA into fp32 acc. K-step = 32.
// C/D mapping (verified): col=lane&15, row=(lane>>4)*4+reg.
// =========================================================================
template<int K>
__global__ __launch_bounds__(256) void mfma_gemm_alpha(
    const float* __restrict__ x,
    const unsigned short* __restrict__ wbhi, const unsigned short* __restrict__ wblo,
    const float* __restrict__ a_s, const float* __restrict__ a_d,
    unsigned short* __restrict__ hout,
    float* __restrict__ asrc, float* __restrict__ adst, int N)
{
    __shared__ float xaf[4][2][64][4];        // [rt][khalf][lane][4 floats] = 8KB
    __shared__ unsigned short wb[32][512];    // [ct*2+plane][lane*8] B-frags = 32KB
    const int t = threadIdx.x, lane = t & 63, wid = t >> 6;
    const int n0 = blockIdx.x * 64;

    f32x4 acc[4][4];
#pragma unroll
    for (int rt = 0; rt < 4; ++rt)
#pragma unroll
        for (int q = 0; q < 4; ++q) acc[rt][q] = (f32x4){0.f, 0.f, 0.f, 0.f};

    for (int kt = 0; kt < K / 32; ++kt){
        __syncthreads();                      // previous iteration reads done
        // stage A (fp32): 8 x 1KB issues, wave wid issues 2
#pragma unroll
        for (int ii = 0; ii < 2; ++ii){
            const int i = wid * 2 + ii;
            const int rt = i >> 1, half = i & 1;
            int node = n0 + rt * 16 + (lane & 15);
            if (node > N - 1) node = N - 1;   // clamp; results discarded later
            const float* src = &x[(size_t)node * K + kt * 32 + 8 * (lane >> 4) + half * 4];
            gload_lds16(src, &xaf[rt][half][0][0]);
        }
        // stage B-frags: 32 x 1KB, wave wid issues 8 (linear, coalesced)
#pragma unroll
        for (int ii = 0; ii < 8; ++ii){
            const int i = wid * 8 + ii;
            const int ct = i >> 1, plane = i & 1;
            const unsigned short* base = plane ? wblo : wbhi;
            gload_lds16(base + ((size_t)(kt * 16 + ct) * 64 + lane) * 8, &wb[i][0]);
        }
        __syncthreads();                      // drains vmcnt (incl. lds loads)

        bf16x8 ahi[4], alo[4];
#pragma unroll
        for (int rt = 0; rt < 4; ++rt){
            const float4 f0 = *(const float4*)&xaf[rt][0][lane][0];
            const float4 f1 = *(const float4*)&xaf[rt][1][lane][0];
            const float fv[8] = {f0.x, f0.y, f0.z, f0.w, f1.x, f1.y, f1.z, f1.w};
#pragma unroll
            for (int j = 0; j < 8; ++j){
                const unsigned short hb = f2bf(fv[j]);
                ahi[rt][j] = (short)hb;
                alo[rt][j] = (short)f2bf(fv[j] - bf2f(hb));
            }
        }

#pragma unroll
        for (int q = 0; q < 4; ++q){
            const int cti = wid * 4 + q;
            const bf16x8 bhi = *(const bf16x8*)&wb[cti * 2 + 0][lane * 8];
            const bf16x8 blo = *(const bf16x8*)&wb[cti * 2 + 1][lane * 8];
#pragma unroll
            for (int rt = 0; rt < 4; ++rt){
                acc[rt][q] = __builtin_amdgcn_mfma_f32_16x16x32_bf16(ahi[rt], bhi, acc[rt][q], 0, 0, 0);
                acc[rt][q] = __builtin_amdgcn_mfma_f32_16x16x32_bf16(alo[rt], bhi, acc[rt][q], 0, 0, 0);
                acc[rt][q] = __builtin_amdgcn_mfma_f32_16x16x32_bf16(ahi[rt], blo, acc[rt][q], 0, 0, 0);
            }
        }
    }

    // ---------------- epilogue: h store (bf16 [node][256]) + alpha reductions ----------------
    const int l15 = lane & 15, lg = lane >> 4;
    float avs[4], avd[4];
#pragma unroll
    for (int q = 0; q < 4; ++q){
        avs[q] = a_s[wid * 64 + q * 16 + l15];
        avd[q] = a_d[wid * 64 + q * 16 + l15];
    }
    float sp[4][4], dp[4][4];
#pragma unroll
    for (int rt = 0; rt < 4; ++rt){
#pragma unroll
        for (int reg = 0; reg < 4; ++reg){
            const int node = n0 + rt * 16 + lg * 4 + reg;
            float s = 0.f, d = 0.f;
            unsigned short hv[4];
#pragma unroll
            for (int q = 0; q < 4; ++q){
                const float v = acc[rt][q][reg];
                s = fmaf(v, avs[q], s); d = fmaf(v, avd[q], d);
                hv[q] = f2bf(v);
            }
            if (node < N){
#pragma unroll
                for (int q = 0; q < 4; ++q)
                    hout[(size_t)node * 256 + (wid * 4 + q) * 16 + l15] = hv[q];
            }
            sp[rt][reg] = s; dp[rt][reg] = d;
        }
    }
#pragma unroll
    for (int off = 1; off <= 8; off <<= 1){
#pragma unroll
        for (int rt = 0; rt < 4; ++rt)
#pragma unroll
            for (int reg = 0; reg < 4; ++reg){
                sp[rt][reg] += __shfl_xor(sp[rt][reg], off, 64);
                dp[rt][reg] += __shfl_xor(dp[rt][reg], off, 64);
            }
    }
    if (l15 == 0){
#pragma unroll
        for (int rt = 0; rt < 4; ++rt)
#pragma unroll
            for (int reg = 0; reg < 4; ++reg){
                const int node = n0 + rt * 16 + lg * 4 + reg;
                if (node < N){
                    asrc[(size_t)node * 4 + wid] = sp[rt][reg];
                    adst[(size_t)node * 4 + wid] = dp[rt][reg];
                }
            }
    }
}

// ============================ CSR build (once) ============================
__global__ void deg_hist_kernel(const int* __restrict__ ei, int E, int* __restrict__ deg){
    int e = blockIdx.x * blockDim.x + threadIdx.x;
    if (e < E) atomicAdd(&deg[ei[E + e]], 1);
}

__global__ __launch_bounds__(256) void part_sum_kernel(const int* __restrict__ deg,
                                                       int* __restrict__ bsum, int N)
{
    __shared__ int red[256];
    const int t = threadIdx.x;
    const int i0 = blockIdx.x * 1024 + t * 4;
    int s = 0;
    if (i0 + 3 < N){
        const int4 v = *(const int4*)&deg[i0];
        s = v.x + v.y + v.z + v.w;
    } else {
#pragma unroll
        for (int j = 0; j < 4; ++j) if (i0 + j < N) s += deg[i0 + j];
    }
    red[t] = s; __syncthreads();
    for (int off = 128; off >= 1; off >>= 1){
        if (t < off) red[t] += red[t + off];
        __syncthreads();
    }
    if (t == 0) bsum[blockIdx.x] = red[0];
}

__global__ __launch_bounds__(256) void scan_part_kernel(int* __restrict__ bsum, int nb,
                                                        int* __restrict__ row, int N)
{
    __shared__ int sh[256];
    const int t = threadIdx.x;
    const int v = (t < nb) ? bsum[t] : 0;
    sh[t] = v; __syncthreads();
    for (int off = 1; off < 256; off <<= 1){
        int u = (t >= off) ? sh[t - off] : 0;
        __syncthreads();
        sh[t] += u;
        __syncthreads();
    }
    if (t < nb) bsum[t] = sh[t] - v;              // exclusive
    if (t == nb - 1) row[N] = sh[t];              // total = E + N
}

__global__ __launch_bounds__(256) void distribute_kernel(const int* __restrict__ deg,
    const int* __restrict__ bsum, int* __restrict__ row, int* __restrict__ cursor, int N)
{
    __shared__ int ts[256];
    const int t = threadIdx.x;
    const int i0 = blockIdx.x * 1024 + t * 4;
    int d[4]; int s = 0;
#pragma unroll
    for (int j = 0; j < 4; ++j){ d[j] = (i0 + j < N) ? deg[i0 + j] : 0; s += d[j]; }
    ts[t] = s; __syncthreads();
    for (int off = 1; off < 256; off <<= 1){
        int u = (t >= off) ? ts[t - off] : 0;
        __syncthreads();
        ts[t] += u;
        __syncthreads();
    }
    int base = bsum[blockIdx.x] + ts[t] - s;      // exclusive prefix for this thread
#pragma unroll
    for (int j = 0; j < 4; ++j){
        if (i0 + j < N){ row[i0 + j] = base; cursor[i0 + j] = base; base += d[j]; }
    }
}

__global__ void scatter_kernel(const int* __restrict__ ei, int E, int N,
                               int* __restrict__ cursor, int* __restrict__ csr)
{
    int e = blockIdx.x * blockDim.x + threadIdx.x;
    if (e >= E + N) return;
    int s, d;
    if (e < E){ s = ei[e]; d = ei[E + e]; } else { s = d = e - E; }
    int pos = atomicAdd(&cursor[d], 1);
    csr[pos] = s;
}

// =========================================================================
// Gather-aggregate per destination node: one wave per node, 4 waves/block.
// h [node][256] bf16; lane owns (head = lane>>4, channels 4*lane..4*lane+3).
// Phase A: lane-parallel p = exp(leakyrelu(e)) -> LDS + denom butterfly.
// Phase B: 2-unrolled gather via byte offsets. Epilogue: /denom+bias+BN+ELU.
//   LAST=false: +nothing, write P0 fp32 [N][256].
//   LAST=true : +residual (fp32 P0), then h2 = P1 . W2 (butterfly) -> outp[node].
// =========================================================================
#define DEG_CAP 128
template<bool LAST>
__global__ __launch_bounds__(256) void agg4_kernel(
    const int* __restrict__ row, const int* __restrict__ csr,
    const float* __restrict__ asrc, const float* __restrict__ adst,
    const unsigned short* __restrict__ h,
    const float* __restrict__ b, const float* __restrict__ g,
    const float* __restrict__ be, const float* __restrict__ mean,
    const float* __restrict__ var,
    const float* __restrict__ res,            // fp32 residual (LAST only)
    float* __restrict__ outp,                 // P0 (layer0) or h2 (LAST)
    const float* __restrict__ W2,             // LAST only
    int N)
{
    __shared__ float plds[4][DEG_CAP * 4];
    __shared__ int   slds[4][DEG_CAP];
    const int wid = threadIdx.x >> 6, lane = threadIdx.x & 63;
    const int node = blockIdx.x * 4 + wid;
    if (node >= N) return;
    const int beg = row[node], end = row[node + 1], deg = end - beg;
    const int degc = deg < DEG_CAP ? deg : DEG_CAP;
    const int head = lane >> 4;

    const float4 ad = *(const float4*)&adst[(size_t)node * 4];

    // ---- phase A: edge weights + denom (lane-parallel) ----
    float d0 = 0.f, d1 = 0.f, d2 = 0.f, d3 = 0.f;
    for (int i = lane; i < deg; i += 64){
        const int s = csr[beg + i];
        const float4 as = *(const float4*)&asrc[(size_t)s * 4];
        float v0 = as.x + ad.x, v1 = as.y + ad.y, v2 = as.z + ad.z, v3 = as.w + ad.w;
        v0 = v0 > 0.f ? v0 : NEG_SLOPE * v0;
        v1 = v1 > 0.f ? v1 : NEG_SLOPE * v1;
        v2 = v2 > 0.f ? v2 : NEG_SLOPE * v2;
        v3 = v3 > 0.f ? v3 : NEG_SLOPE * v3;
        const float p0 = __expf(v0), p1 = __expf(v1);
        const float p2 = __expf(v2), p3 = __expf(v3);
        d0 += p0; d1 += p1; d2 += p2; d3 += p3;
        if (i < DEG_CAP){
            *(float4*)&plds[wid][i * 4] = make_float4(p0, p1, p2, p3);
            slds[wid][i] = s << 9;               // byte offset of h row
        }
    }
    for (int off = 32; off >= 1; off >>= 1){
        d0 += __shfl_xor(d0, off, 64); d1 += __shfl_xor(d1, off, 64);
        d2 += __shfl_xor(d2, off, 64); d3 += __shfl_xor(d3, off, 64);
    }

    // ---- phase B: weighted gather-accumulate ----
    float a0 = 0.f, a1 = 0.f, a2 = 0.f, a3 = 0.f;
    {
        const char* hb = (const char*)h + lane * 8;
        const float* pb = &plds[wid][0];
        const int* sb = &slds[wid][0];
#define EDGE_BODY(slot)                                                        \
        {                                                                      \
            const float p_ = pb[(slot) * 4 + head];                            \
            const ushort4 hv_ = *(const ushort4*)(hb + sb[slot]);              \
            a0 = fmaf(p_, bf2f(hv_.x), a0); a1 = fmaf(p_, bf2f(hv_.y), a1);    \
            a2 = fmaf(p_, bf2f(hv_.z), a2); a3 = fmaf(p_, bf2f(hv_.w), a3);    \
        }
        int i = 0;
        for (; i + 2 <= degc; i += 2){
            EDGE_BODY(i);
            EDGE_BODY(i + 1);
        }
        for (; i < degc; ++i) EDGE_BODY(i);
#undef EDGE_BODY
    }

    // overflow path (deg > DEG_CAP): recompute p inline (statistically never)
    for (int jj = beg + DEG_CAP; jj < end; ++jj){
        const int s = csr[jj];
        const float4 as = *(const float4*)&asrc[(size_t)s * 4];
        float e0 = as.x + ad.x, e1 = as.y + ad.y, e2 = as.z + ad.z, e3 = as.w + ad.w;
        float eh = (head == 0) ? e0 : (head == 1) ? e1 : (head == 2) ? e2 : e3;
        eh = eh > 0.f ? eh : NEG_SLOPE * eh;
        const float p = __expf(eh);
        const ushort4 hv = *(const ushort4*)&h[(size_t)s * 256 + lane * 4];
        a0 = fmaf(p, bf2f(hv.x), a0); a1 = fmaf(p, bf2f(hv.y), a1);
        a2 = fmaf(p, bf2f(hv.z), a2); a3 = fmaf(p, bf2f(hv.w), a3);
    }

    // ---- fused epilogue ----
    const int l15 = lane & 15;
    const float dsel = (head == 0) ? d0 : (head == 1) ? d1 : (head == 2) ? d2 : d3;
    const float rdi = 1.f / dsel;
    const int c0 = head * 64 + 4 * l15;
    const float4 bv  = *(const float4*)&b[c0];
    const float4 gv  = *(const float4*)&g[c0];
    const float4 bev = *(const float4*)&be[c0];
    const float4 mv  = *(const float4*)&mean[c0];
    const float4 vv4 = *(const float4*)&var[c0];
    const float ava[4]  = {a0, a1, a2, a3};
    const float bva[4]  = {bv.x, bv.y, bv.z, bv.w};
    const float gva[4]  = {gv.x, gv.y, gv.z, gv.w};
    const float beva[4] = {bev.x, bev.y, bev.z, bev.w};
    const float mva[4]  = {mv.x, mv.y, mv.z, mv.w};
    const float vva[4]  = {vv4.x, vv4.y, vv4.z, vv4.w};
    float rh[4] = {0.f, 0.f, 0.f, 0.f};
    if (LAST){
        const float4 rv = *(const float4*)&res[(size_t)node * 256 + c0];
        rh[0] = rv.x; rh[1] = rv.y; rh[2] = rv.z; rh[3] = rv.w;
    }
    float vvv[4];
#pragma unroll
    for (int j = 0; j < 4; ++j){
        float v = ava[j] * rdi + bva[j];
        v = (v - mva[j]) * (gva[j] * rsqrtf(vva[j] + BN_EPS)) + beva[j];
        v = v > 0.f ? v : (__expf(v) - 1.f);
        vvv[j] = v + rh[j];
    }
    if (!LAST){
        *(float4*)&outp[(size_t)node * 256 + c0] =
            make_float4(vvv[0], vvv[1], vvv[2], vvv[3]);
    } else {
        const float4 w2v = *(const float4*)&W2[c0];
        float part = vvv[0] * w2v.x + vvv[1] * w2v.y + vvv[2] * w2v.z + vvv[3] * w2v.w;
        for (int off = 32; off >= 1; off >>= 1) part += __shfl_xor(part, off, 64);
        if (lane == 0) outp[node] = part;         // h2[node]
    }
}

// ------------------------- layer 2 aggregate (heads=1, C=1) -------------------------
__global__ void agg2_kernel(const int* __restrict__ row, const int* __restrict__ csr,
                            const float* __restrict__ h2,
                            const float* __restrict__ as2, const float* __restrict__ ad2,
                            const float* __restrict__ b2, float* __restrict__ out, int N)
{
    const int n = blockIdx.x * blockDim.x + threadIdx.x;
    if (n >= N) return;
    const float A_s = as2[0];
    const float hd  = h2[n] * ad2[0];
    const int beg = row[n], end = row[n + 1];
    float den = 0.f, acc = 0.f;
    for (int i = beg; i < end; ++i){
        const float hv = h2[csr[i]];
        float a = fmaf(A_s, hv, hd);
        a = a > 0.f ? a : NEG_SLOPE * a;
        const float p = __expf(a);
        den += p; acc = fmaf(p, hv, acc);
    }
    out[n] = acc / den + b2[0];
}

// =========================================================================
extern "C" void kernel_launch(void* const* d_in, const int* in_sizes, int n_in,
                              void* d_out, int out_size, void* d_ws, size_t ws_size,
                              hipStream_t stream)
{
    const float* x   = (const float*)d_in[0];
    const int*   ei  = (const int*)  d_in[1];
    const float* W0  = (const float*)d_in[2];
    const float* as0 = (const float*)d_in[3];
    const float* ad0 = (const float*)d_in[4];
    const float* b0  = (const float*)d_in[5];
    const float* W1  = (const float*)d_in[6];
    const float* as1 = (const float*)d_in[7];
    const float* ad1 = (const float*)d_in[8];
    const float* b1  = (const float*)d_in[9];
    const float* W2  = (const float*)d_in[10];
    const float* as2 = (const float*)d_in[11];
    const float* ad2 = (const float*)d_in[12];
    const float* b2  = (const float*)d_in[13];
    const float* g0  = (const float*)d_in[14];
    const float* be0 = (const float*)d_in[15];
    const float* m0  = (const float*)d_in[16];
    const float* v0  = (const float*)d_in[17];
    const float* g1  = (const float*)d_in[18];
    const float* be1 = (const float*)d_in[19];
    const float* m1  = (const float*)d_in[20];
    const float* v1  = (const float*)d_in[21];

    const int N = in_sizes[0] / 128;
    const int E = in_sizes[1] / 2;
    const int EN = E + N;

    // ---- workspace layout ----
    char* w = (char*)d_ws;
    unsigned short* H  = (unsigned short*)w;  w += (size_t)N * 256 * 2;   // h bf16 [N][256]
    float*    P0     = (float*)w;   w += (size_t)N * 256 * 4;             // layer0 out fp32
    float*    asrc   = (float*)w;   w += (size_t)N * 4 * 4;
    float*    adst   = (float*)w;   w += (size_t)N * 4 * 4;
    int*      deg    = (int*)w;     w += (size_t)N * 4;
    int*      cursor = (int*)w;     w += (size_t)N * 4;
    int*      csr    = (int*)w;     w += (size_t)EN * 4;
    float*    h2     = (float*)w;   w += (size_t)N * 4;
    int*      bsum   = (int*)w;     w += 1024;
    unsigned short* Wb0hi = (unsigned short*)w; w += (size_t)128 * 256 * 2;
    unsigned short* Wb0lo = (unsigned short*)w; w += (size_t)128 * 256 * 2;
    unsigned short* Wb1hi = (unsigned short*)w; w += (size_t)256 * 256 * 2;
    unsigned short* Wb1lo = (unsigned short*)w; w += (size_t)256 * 256 * 2;
    int*      rowp   = (int*)w;     w += (size_t)(N + 1) * 4;   // last (odd size)

    const int gN64  = (N + 63) / 64;
    const int gN4   = (N + 3) / 4;
    const int gNt   = (N + 255) / 256;
    const int gE    = (E + 255) / 256;
    const int gEN   = (EN + 255) / 256;
    const int nb    = (N + 1023) / 1024;

    // ---------------- one-time prep: W repack + deg_init (fused), CSR ----------------
    prep_kernel<<<384 + gNt, 256, 0, stream>>>(W0, Wb0hi, Wb0lo, W1, Wb1hi, Wb1lo, deg, N);
    deg_hist_kernel<<<gE, 256, 0, stream>>>(ei, E, deg);
    part_sum_kernel<<<nb, 256, 0, stream>>>(deg, bsum, N);
    scan_part_kernel<<<1, 256, 0, stream>>>(bsum, nb, rowp, N);
    distribute_kernel<<<nb, 256, 0, stream>>>(deg, bsum, rowp, cursor, N);
    scatter_kernel<<<gEN, 256, 0, stream>>>(ei, E, N, cursor, csr);

    // ---------------- layer 0 ----------------
    mfma_gemm_alpha<128><<<gN64, 256, 0, stream>>>(x, Wb0hi, Wb0lo,
                                                   as0, ad0, H, asrc, adst, N);
    agg4_kernel<false><<<gN4, 256, 0, stream>>>(rowp, csr, asrc, adst, H,
                                                b0, g0, be0, m0, v0,
                                                nullptr, P0, nullptr, N);

    // ---------------- layer 1 (+ fused h2 = P1 . W2) ----------------
    mfma_gemm_alpha<256><<<gN64, 256, 0, stream>>>(P0, Wb1hi, Wb1lo,
                                                   as1, ad1, H, asrc, adst, N);
    agg4_kernel<true><<<gN4, 256, 0, stream>>>(rowp, csr, asrc, adst, H,
                                               b1, g1, be1, m1, v1,
                                               P0, h2, W2, N);

    // ---------------- layer 2 ----------------
    agg2_kernel<<<gNt, 256, 0, stream>>>(rowp, csr, h2, as2, ad2, b2, (float*)d_out, N);
}

// Round 11
// 321.062 us; speedup vs baseline: 1.4267x; 1.0327x over previous
//
#include <hip/hip_runtime.h>
#include <math.h>

#define NEG_SLOPE 0.2f
#define BN_EPS 1e-5f

typedef __attribute__((ext_vector_type(8))) short bf16x8;
typedef __attribute__((ext_vector_type(4))) float f32x4;

static __device__ __forceinline__ unsigned short f2bf(float f){
    unsigned u = __float_as_uint(f);
    u += 0x7FFFu + ((u >> 16) & 1u);          // round-to-nearest-even
    return (unsigned short)(u >> 16);
}
static __device__ __forceinline__ float bf2f(unsigned short v){
    return __uint_as_float((unsigned)v << 16);
}

// async global->LDS, 16B/lane; LDS dest wave-uniform base + lane*16
static __device__ __forceinline__ void gload_lds16(const void* g, void* l){
    __builtin_amdgcn_global_load_lds(
        (const __attribute__((address_space(1))) void*)g,
        (__attribute__((address_space(3))) void*)l, 16, 0, 0);
}

// ---- fused prep: repack W0, W1 to MFMA B-frag hi/lo planes + deg_init ----
static __device__ __forceinline__ void repack_one(const float* __restrict__ W,
    unsigned short* __restrict__ whi, unsigned short* __restrict__ wlo, int o)
{
    const int j = o & 7, ln = (o >> 3) & 63, ct = (o >> 9) & 15, kt = o >> 13;
    const int k = kt * 32 + 8 * (ln >> 4) + j;
    const int col = ct * 16 + (ln & 15);
    const float v = W[k * 256 + col];
    const unsigned short hb = f2bf(v);
    whi[o] = hb; wlo[o] = f2bf(v - bf2f(hb));
}

__global__ void prep_kernel(const float* __restrict__ W0,
    unsigned short* __restrict__ w0hi, unsigned short* __restrict__ w0lo,
    const float* __restrict__ W1,
    unsigned short* __restrict__ w1hi, unsigned short* __restrict__ w1lo,
    int* __restrict__ deg, int N)
{
    const int bid = blockIdx.x, t = threadIdx.x;
    if (bid < 128){
        repack_one(W0, w0hi, w0lo, bid * 256 + t);
    } else if (bid < 384){
        repack_one(W1, w1hi, w1lo, (bid - 128) * 256 + t);
    } else {
        const int i = (bid - 384) * 256 + t;
        if (i < N) deg[i] = 1;                // self-loop
    }
}

// =========================================================================
// Layer-0 MFMA GEMM: x fp32 [N][128]; hi/lo bf16 split IN-REGISTER.
// Block = 4 waves = 64-node tile; wave w = head w (col-tiles w*4..w*4+3).
// 3-pass hi/lo MFMA. C/D map (verified): col=lane&15, row=(lane>>4)*4+reg.
// =========================================================================
__global__ __launch_bounds__(256) void mfma_gemm0(
    const float* __restrict__ x,
    const unsigned short* __restrict__ wbhi, const unsigned short* __restrict__ wblo,
    const float* __restrict__ a_s, const float* __restrict__ a_d,
    unsigned short* __restrict__ hout,
    float* __restrict__ asrc, float* __restrict__ adst, int N)
{
    constexpr int K = 128;
    __shared__ float xaf[4][2][64][4];        // 8KB
    __shared__ unsigned short wb[32][512];    // 32KB
    const int t = threadIdx.x, lane = t & 63, wid = t >> 6;
    const int n0 = blockIdx.x * 64;

    f32x4 acc[4][4];
#pragma unroll
    for (int rt = 0; rt < 4; ++rt)
#pragma unroll
        for (int q = 0; q < 4; ++q) acc[rt][q] = (f32x4){0.f, 0.f, 0.f, 0.f};

    for (int kt = 0; kt < K / 32; ++kt){
        __syncthreads();
#pragma unroll
        for (int ii = 0; ii < 2; ++ii){
            const int i = wid * 2 + ii;
            const int rt = i >> 1, half = i & 1;
            int node = n0 + rt * 16 + (lane & 15);
            if (node > N - 1) node = N - 1;
            const float* src = &x[(size_t)node * K + kt * 32 + 8 * (lane >> 4) + half * 4];
            gload_lds16(src, &xaf[rt][half][0][0]);
        }
#pragma unroll
        for (int ii = 0; ii < 8; ++ii){
            const int i = wid * 8 + ii;
            const int ct = i >> 1, plane = i & 1;
            const unsigned short* base = plane ? wblo : wbhi;
            gload_lds16(base + ((size_t)(kt * 16 + ct) * 64 + lane) * 8, &wb[i][0]);
        }
        __syncthreads();

        bf16x8 ahi[4], alo[4];
#pragma unroll
        for (int rt = 0; rt < 4; ++rt){
            const float4 f0 = *(const float4*)&xaf[rt][0][lane][0];
            const float4 f1 = *(const float4*)&xaf[rt][1][lane][0];
            const float fv[8] = {f0.x, f0.y, f0.z, f0.w, f1.x, f1.y, f1.z, f1.w};
#pragma unroll
            for (int j = 0; j < 8; ++j){
                const unsigned short hb = f2bf(fv[j]);
                ahi[rt][j] = (short)hb;
                alo[rt][j] = (short)f2bf(fv[j] - bf2f(hb));
            }
        }

#pragma unroll
        for (int q = 0; q < 4; ++q){
            const int cti = wid * 4 + q;
            const bf16x8 bhi = *(const bf16x8*)&wb[cti * 2 + 0][lane * 8];
            const bf16x8 blo = *(const bf16x8*)&wb[cti * 2 + 1][lane * 8];
#pragma unroll
            for (int rt = 0; rt < 4; ++rt){
                acc[rt][q] = __builtin_amdgcn_mfma_f32_16x16x32_bf16(ahi[rt], bhi, acc[rt][q], 0, 0, 0);
                acc[rt][q] = __builtin_amdgcn_mfma_f32_16x16x32_bf16(alo[rt], bhi, acc[rt][q], 0, 0, 0);
                acc[rt][q] = __builtin_amdgcn_mfma_f32_16x16x32_bf16(ahi[rt], blo, acc[rt][q], 0, 0, 0);
            }
        }
    }

    // epilogue: h store + alpha reductions
    const int l15 = lane & 15, lg = lane >> 4;
    float avs[4], avd[4];
#pragma unroll
    for (int q = 0; q < 4; ++q){
        avs[q] = a_s[wid * 64 + q * 16 + l15];
        avd[q] = a_d[wid * 64 + q * 16 + l15];
    }
    float sp[4][4], dp[4][4];
#pragma unroll
    for (int rt = 0; rt < 4; ++rt){
#pragma unroll
        for (int reg = 0; reg < 4; ++reg){
            const int node = n0 + rt * 16 + lg * 4 + reg;
            float s = 0.f, d = 0.f;
            unsigned short hv[4];
#pragma unroll
            for (int q = 0; q < 4; ++q){
                const float v = acc[rt][q][reg];
                s = fmaf(v, avs[q], s); d = fmaf(v, avd[q], d);
                hv[q] = f2bf(v);
            }
            if (node < N){
#pragma unroll
                for (int q = 0; q < 4; ++q)
                    hout[(size_t)node * 256 + (wid * 4 + q) * 16 + l15] = hv[q];
            }
            sp[rt][reg] = s; dp[rt][reg] = d;
        }
    }
#pragma unroll
    for (int off = 1; off <= 8; off <<= 1){
#pragma unroll
        for (int rt = 0; rt < 4; ++rt)
#pragma unroll
            for (int reg = 0; reg < 4; ++reg){
                sp[rt][reg] += __shfl_xor(sp[rt][reg], off, 64);
                dp[rt][reg] += __shfl_xor(dp[rt][reg], off, 64);
            }
    }
    if (l15 == 0){
#pragma unroll
        for (int rt = 0; rt < 4; ++rt)
#pragma unroll
            for (int reg = 0; reg < 4; ++reg){
                const int node = n0 + rt * 16 + lg * 4 + reg;
                if (node < N){
                    asrc[(size_t)node * 4 + wid] = sp[rt][reg];
                    adst[(size_t)node * 4 + wid] = dp[rt][reg];
                }
            }
    }
}

// =========================================================================
// Layer-1 MFMA GEMM: input P0 bf16 [N][256] (single plane) -> 2-MFMA (Whi+Wlo).
// =========================================================================
__global__ __launch_bounds__(256) void mfma_gemm1(
    const unsigned short* __restrict__ xb,
    const unsigned short* __restrict__ wbhi, const unsigned short* __restrict__ wblo,
    const float* __restrict__ a_s, const float* __restrict__ a_d,
    unsigned short* __restrict__ hout,
    float* __restrict__ asrc, float* __restrict__ adst, int N)
{
    constexpr int K = 256;
    __shared__ unsigned short xab[4][512];    // 4KB (A-frags, one per rt)
    __shared__ unsigned short wb[32][512];    // 32KB
    const int t = threadIdx.x, lane = t & 63, wid = t >> 6;
    const int n0 = blockIdx.x * 64;

    f32x4 acc[4][4];
#pragma unroll
    for (int rt = 0; rt < 4; ++rt)
#pragma unroll
        for (int q = 0; q < 4; ++q) acc[rt][q] = (f32x4){0.f, 0.f, 0.f, 0.f};

    for (int kt = 0; kt < K / 32; ++kt){
        __syncthreads();
        {   // stage A: wave wid stages rt = wid (1KB each)
            const int rt = wid;
            int node = n0 + rt * 16 + (lane & 15);
            if (node > N - 1) node = N - 1;
            const unsigned short* src = &xb[(size_t)node * K + kt * 32 + 8 * (lane >> 4)];
            gload_lds16(src, &xab[rt][0]);
        }
#pragma unroll
        for (int ii = 0; ii < 8; ++ii){
            const int i = wid * 8 + ii;
            const int ct = i >> 1, plane = i & 1;
            const unsigned short* base = plane ? wblo : wbhi;
            gload_lds16(base + ((size_t)(kt * 16 + ct) * 64 + lane) * 8, &wb[i][0]);
        }
        __syncthreads();

        bf16x8 a[4];
#pragma unroll
        for (int rt = 0; rt < 4; ++rt)
            a[rt] = *(const bf16x8*)&xab[rt][lane * 8];

#pragma unroll
        for (int q = 0; q < 4; ++q){
            const int cti = wid * 4 + q;
            const bf16x8 bhi = *(const bf16x8*)&wb[cti * 2 + 0][lane * 8];
            const bf16x8 blo = *(const bf16x8*)&wb[cti * 2 + 1][lane * 8];
#pragma unroll
            for (int rt = 0; rt < 4; ++rt){
                acc[rt][q] = __builtin_amdgcn_mfma_f32_16x16x32_bf16(a[rt], bhi, acc[rt][q], 0, 0, 0);
                acc[rt][q] = __builtin_amdgcn_mfma_f32_16x16x32_bf16(a[rt], blo, acc[rt][q], 0, 0, 0);
            }
        }
    }

    // epilogue: identical structure
    const int l15 = lane & 15, lg = lane >> 4;
    float avs[4], avd[4];
#pragma unroll
    for (int q = 0; q < 4; ++q){
        avs[q] = a_s[wid * 64 + q * 16 + l15];
        avd[q] = a_d[wid * 64 + q * 16 + l15];
    }
    float sp[4][4], dp[4][4];
#pragma unroll
    for (int rt = 0; rt < 4; ++rt){
#pragma unroll
        for (int reg = 0; reg < 4; ++reg){
            const int node = n0 + rt * 16 + lg * 4 + reg;
            float s = 0.f, d = 0.f;
            unsigned short hv[4];
#pragma unroll
            for (int q = 0; q < 4; ++q){
                const float v = acc[rt][q][reg];
                s = fmaf(v, avs[q], s); d = fmaf(v, avd[q], d);
                hv[q] = f2bf(v);
            }
            if (node < N){
#pragma unroll
                for (int q = 0; q < 4; ++q)
                    hout[(size_t)node * 256 + (wid * 4 + q) * 16 + l15] = hv[q];
            }
            sp[rt][reg] = s; dp[rt][reg] = d;
        }
    }
#pragma unroll
    for (int off = 1; off <= 8; off <<= 1){
#pragma unroll
        for (int rt = 0; rt < 4; ++rt)
#pragma unroll
            for (int reg = 0; reg < 4; ++reg){
                sp[rt][reg] += __shfl_xor(sp[rt][reg], off, 64);
                dp[rt][reg] += __shfl_xor(dp[rt][reg], off, 64);
            }
    }
    if (l15 == 0){
#pragma unroll
        for (int rt = 0; rt < 4; ++rt)
#pragma unroll
            for (int reg = 0; reg < 4; ++reg){
                const int node = n0 + rt * 16 + lg * 4 + reg;
                if (node < N){
                    asrc[(size_t)node * 4 + wid] = sp[rt][reg];
                    adst[(size_t)node * 4 + wid] = dp[rt][reg];
                }
            }
    }
}

// ============================ CSR build (once) ============================
__global__ void deg_hist_kernel(const int* __restrict__ ei, int E, int* __restrict__ deg){
    int e = blockIdx.x * blockDim.x + threadIdx.x;
    if (e < E) atomicAdd(&deg[ei[E + e]], 1);
}

__global__ __launch_bounds__(256) void part_sum_kernel(const int* __restrict__ deg,
                                                       int* __restrict__ bsum, int N)
{
    __shared__ int red[256];
    const int t = threadIdx.x;
    const int i0 = blockIdx.x * 1024 + t * 4;
    int s = 0;
    if (i0 + 3 < N){
        const int4 v = *(const int4*)&deg[i0];
        s = v.x + v.y + v.z + v.w;
    } else {
#pragma unroll
        for (int j = 0; j < 4; ++j) if (i0 + j < N) s += deg[i0 + j];
    }
    red[t] = s; __syncthreads();
    for (int off = 128; off >= 1; off >>= 1){
        if (t < off) red[t] += red[t + off];
        __syncthreads();
    }
    if (t == 0) bsum[blockIdx.x] = red[0];
}

__global__ __launch_bounds__(256) void scan_part_kernel(int* __restrict__ bsum, int nb,
                                                        int* __restrict__ row, int N)
{
    __shared__ int sh[256];
    const int t = threadIdx.x;
    const int v = (t < nb) ? bsum[t] : 0;
    sh[t] = v; __syncthreads();
    for (int off = 1; off < 256; off <<= 1){
        int u = (t >= off) ? sh[t - off] : 0;
        __syncthreads();
        sh[t] += u;
        __syncthreads();
    }
    if (t < nb) bsum[t] = sh[t] - v;              // exclusive
    if (t == nb - 1) row[N] = sh[t];              // total = E + N
}

__global__ __launch_bounds__(256) void distribute_kernel(const int* __restrict__ deg,
    const int* __restrict__ bsum, int* __restrict__ row, int* __restrict__ cursor, int N)
{
    __shared__ int ts[256];
    const int t = threadIdx.x;
    const int i0 = blockIdx.x * 1024 + t * 4;
    int d[4]; int s = 0;
#pragma unroll
    for (int j = 0; j < 4; ++j){ d[j] = (i0 + j < N) ? deg[i0 + j] : 0; s += d[j]; }
    ts[t] = s; __syncthreads();
    for (int off = 1; off < 256; off <<= 1){
        int u = (t >= off) ? ts[t - off] : 0;
        __syncthreads();
        ts[t] += u;
        __syncthreads();
    }
    int base = bsum[blockIdx.x] + ts[t] - s;
#pragma unroll
    for (int j = 0; j < 4; ++j){
        if (i0 + j < N){ row[i0 + j] = base; cursor[i0 + j] = base; base += d[j]; }
    }
}

__global__ void scatter_kernel(const int* __restrict__ ei, int E, int N,
                               int* __restrict__ cursor, int* __restrict__ csr)
{
    int e = blockIdx.x * blockDim.x + threadIdx.x;
    if (e >= E + N) return;
    int s, d;
    if (e < E){ s = ei[e]; d = ei[E + e]; } else { s = d = e - E; }
    int pos = atomicAdd(&cursor[d], 1);
    csr[pos] = s;
}

// =========================================================================
// Gather-aggregate: one wave per node, 4 waves/block. h [node][256] bf16;
// lane owns (head = lane>>4, channels 4*lane..4*lane+3).
// Phase A: lane-parallel p=exp(leakyrelu(e)) -> LDS + denom butterfly.
// Phase B: batch-8 gather (8 rows in flight). Epilogue /denom+bias+BN+ELU.
//   LAST=false: write P0 bf16 [N][256].
//   LAST=true : + residual (bf16 P0), h2 = P1 . W2 butterfly -> outp[node].
// =========================================================================
#define DEG_CAP 128
template<bool LAST>
__global__ __launch_bounds__(256) void agg4_kernel(
    const int* __restrict__ row, const int* __restrict__ csr,
    const float* __restrict__ asrc, const float* __restrict__ adst,
    const unsigned short* __restrict__ h,
    const float* __restrict__ b, const float* __restrict__ g,
    const float* __restrict__ be, const float* __restrict__ mean,
    const float* __restrict__ var,
    const unsigned short* __restrict__ res,   // bf16 residual (LAST only)
    unsigned short* __restrict__ outbf,       // P0 bf16 (layer0)
    float* __restrict__ outh2,                // h2 (LAST)
    const float* __restrict__ W2,             // LAST only
    int N)
{
    __shared__ float plds[4][DEG_CAP * 4];
    __shared__ int   slds[4][DEG_CAP];
    const int wid = threadIdx.x >> 6, lane = threadIdx.x & 63;
    const int node = blockIdx.x * 4 + wid;
    if (node >= N) return;
    const int beg = row[node], end = row[node + 1], deg = end - beg;
    const int degc = deg < DEG_CAP ? deg : DEG_CAP;
    const int head = lane >> 4;

    const float4 ad = *(const float4*)&adst[(size_t)node * 4];

    // ---- phase A ----
    float d0 = 0.f, d1 = 0.f, d2 = 0.f, d3 = 0.f;
    for (int i = lane; i < deg; i += 64){
        const int s = csr[beg + i];
        const float4 as = *(const float4*)&asrc[(size_t)s * 4];
        float v0 = as.x + ad.x, v1 = as.y + ad.y, v2 = as.z + ad.z, v3 = as.w + ad.w;
        v0 = v0 > 0.f ? v0 : NEG_SLOPE * v0;
        v1 = v1 > 0.f ? v1 : NEG_SLOPE * v1;
        v2 = v2 > 0.f ? v2 : NEG_SLOPE * v2;
        v3 = v3 > 0.f ? v3 : NEG_SLOPE * v3;
        const float p0 = __expf(v0), p1 = __expf(v1);
        const float p2 = __expf(v2), p3 = __expf(v3);
        d0 += p0; d1 += p1; d2 += p2; d3 += p3;
        if (i < DEG_CAP){
            *(float4*)&plds[wid][i * 4] = make_float4(p0, p1, p2, p3);
            slds[wid][i] = s << 9;               // byte offset of h row
        }
    }
    for (int off = 32; off >= 1; off >>= 1){
        d0 += __shfl_xor(d0, off, 64); d1 += __shfl_xor(d1, off, 64);
        d2 += __shfl_xor(d2, off, 64); d3 += __shfl_xor(d3, off, 64);
    }

    // ---- phase B: batch-8 gather-accumulate ----
    float a0 = 0.f, a1 = 0.f, a2 = 0.f, a3 = 0.f;
    {
        const char* hb = (const char*)h + lane * 8;
        const float* pb = &plds[wid][0];
        const int* sb = &slds[wid][0];
        int i = 0;
        for (; i + 8 <= degc; i += 8){
            ushort4 hv[8];
#pragma unroll
            for (int u = 0; u < 8; ++u) hv[u] = *(const ushort4*)(hb + sb[i + u]);
#pragma unroll
            for (int u = 0; u < 8; ++u){
                const float p_ = pb[(i + u) * 4 + head];
                a0 = fmaf(p_, bf2f(hv[u].x), a0); a1 = fmaf(p_, bf2f(hv[u].y), a1);
                a2 = fmaf(p_, bf2f(hv[u].z), a2); a3 = fmaf(p_, bf2f(hv[u].w), a3);
            }
        }
        for (; i < degc; ++i){
            const float p_ = pb[i * 4 + head];
            const ushort4 hv_ = *(const ushort4*)(hb + sb[i]);
            a0 = fmaf(p_, bf2f(hv_.x), a0); a1 = fmaf(p_, bf2f(hv_.y), a1);
            a2 = fmaf(p_, bf2f(hv_.z), a2); a3 = fmaf(p_, bf2f(hv_.w), a3);
        }
    }

    // overflow path (deg > DEG_CAP): statistically never
    for (int jj = beg + DEG_CAP; jj < end; ++jj){
        const int s = csr[jj];
        const float4 as = *(const float4*)&asrc[(size_t)s * 4];
        float e0 = as.x + ad.x, e1 = as.y + ad.y, e2 = as.z + ad.z, e3 = as.w + ad.w;
        float eh = (head == 0) ? e0 : (head == 1) ? e1 : (head == 2) ? e2 : e3;
        eh = eh > 0.f ? eh : NEG_SLOPE * eh;
        const float p = __expf(eh);
        const ushort4 hv = *(const ushort4*)&h[(size_t)s * 256 + lane * 4];
        a0 = fmaf(p, bf2f(hv.x), a0); a1 = fmaf(p, bf2f(hv.y), a1);
        a2 = fmaf(p, bf2f(hv.z), a2); a3 = fmaf(p, bf2f(hv.w), a3);
    }

    // ---- fused epilogue ----
    const int l15 = lane & 15;
    const float dsel = (head == 0) ? d0 : (head == 1) ? d1 : (head == 2) ? d2 : d3;
    const float rdi = 1.f / dsel;
    const int c0 = head * 64 + 4 * l15;
    const float4 bv  = *(const float4*)&b[c0];
    const float4 gv  = *(const float4*)&g[c0];
    const float4 bev = *(const float4*)&be[c0];
    const float4 mv  = *(const float4*)&mean[c0];
    const float4 vv4 = *(const float4*)&var[c0];
    const float ava[4]  = {a0, a1, a2, a3};
    const float bva[4]  = {bv.x, bv.y, bv.z, bv.w};
    const float gva[4]  = {gv.x, gv.y, gv.z, gv.w};
    const float beva[4] = {bev.x, bev.y, bev.z, bev.w};
    const float mva[4]  = {mv.x, mv.y, mv.z, mv.w};
    const float vva[4]  = {vv4.x, vv4.y, vv4.z, vv4.w};
    float rh[4] = {0.f, 0.f, 0.f, 0.f};
    if (LAST){
        const ushort4 rv = *(const ushort4*)&res[(size_t)node * 256 + c0];
        rh[0] = bf2f(rv.x); rh[1] = bf2f(rv.y); rh[2] = bf2f(rv.z); rh[3] = bf2f(rv.w);
    }
    float vvv[4];
#pragma unroll
    for (int j = 0; j < 4; ++j){
        float v = ava[j] * rdi + bva[j];
        v = (v - mva[j]) * (gva[j] * rsqrtf(vva[j] + BN_EPS)) + beva[j];
        v = v > 0.f ? v : (__expf(v) - 1.f);
        vvv[j] = v + rh[j];
    }
    if (!LAST){
        ushort4 o4;
        o4.x = f2bf(vvv[0]); o4.y = f2bf(vvv[1]);
        o4.z = f2bf(vvv[2]); o4.w = f2bf(vvv[3]);
        *(ushort4*)&outbf[(size_t)node * 256 + c0] = o4;
    } else {
        const float4 w2v = *(const float4*)&W2[c0];
        float part = vvv[0] * w2v.x + vvv[1] * w2v.y + vvv[2] * w2v.z + vvv[3] * w2v.w;
        for (int off = 32; off >= 1; off >>= 1) part += __shfl_xor(part, off, 64);
        if (lane == 0) outh2[node] = part;        // h2[node]
    }
}

// ------------------------- layer 2 aggregate (heads=1, C=1) -------------------------
__global__ void agg2_kernel(const int* __restrict__ row, const int* __restrict__ csr,
                            const float* __restrict__ h2,
                            const float* __restrict__ as2, const float* __restrict__ ad2,
                            const float* __restrict__ b2, float* __restrict__ out, int N)
{
    const int n = blockIdx.x * blockDim.x + threadIdx.x;
    if (n >= N) return;
    const float A_s = as2[0];
    const float hd  = h2[n] * ad2[0];
    const int beg = row[n], end = row[n + 1];
    float den = 0.f, acc = 0.f;
    for (int i = beg; i < end; ++i){
        const float hv = h2[csr[i]];
        float a = fmaf(A_s, hv, hd);
        a = a > 0.f ? a : NEG_SLOPE * a;
        const float p = __expf(a);
        den += p; acc = fmaf(p, hv, acc);
    }
    out[n] = acc / den + b2[0];
}

// =========================================================================
extern "C" void kernel_launch(void* const* d_in, const int* in_sizes, int n_in,
                              void* d_out, int out_size, void* d_ws, size_t ws_size,
                              hipStream_t stream)
{
    const float* x   = (const float*)d_in[0];
    const int*   ei  = (const int*)  d_in[1];
    const float* W0  = (const float*)d_in[2];
    const float* as0 = (const float*)d_in[3];
    const float* ad0 = (const float*)d_in[4];
    const float* b0  = (const float*)d_in[5];
    const float* W1  = (const float*)d_in[6];
    const float* as1 = (const float*)d_in[7];
    const float* ad1 = (const float*)d_in[8];
    const float* b1  = (const float*)d_in[9];
    const float* W2  = (const float*)d_in[10];
    const float* as2 = (const float*)d_in[11];
    const float* ad2 = (const float*)d_in[12];
    const float* b2  = (const float*)d_in[13];
    const float* g0  = (const float*)d_in[14];
    const float* be0 = (const float*)d_in[15];
    const float* m0  = (const float*)d_in[16];
    const float* v0  = (const float*)d_in[17];
    const float* g1  = (const float*)d_in[18];
    const float* be1 = (const float*)d_in[19];
    const float* m1  = (const float*)d_in[20];
    const float* v1  = (const float*)d_in[21];

    const int N = in_sizes[0] / 128;
    const int E = in_sizes[1] / 2;
    const int EN = E + N;

    // ---- workspace layout ----
    char* w = (char*)d_ws;
    unsigned short* H    = (unsigned short*)w;  w += (size_t)N * 256 * 2;  // h bf16 [N][256]
    unsigned short* P0   = (unsigned short*)w;  w += (size_t)N * 256 * 2;  // layer0 out bf16
    float*    asrc   = (float*)w;   w += (size_t)N * 4 * 4;
    float*    adst   = (float*)w;   w += (size_t)N * 4 * 4;
    int*      deg    = (int*)w;     w += (size_t)N * 4;
    int*      cursor = (int*)w;     w += (size_t)N * 4;
    int*      csr    = (int*)w;     w += (size_t)EN * 4;
    float*    h2     = (float*)w;   w += (size_t)N * 4;
    int*      bsum   = (int*)w;     w += 1024;
    unsigned short* Wb0hi = (unsigned short*)w; w += (size_t)128 * 256 * 2;
    unsigned short* Wb0lo = (unsigned short*)w; w += (size_t)128 * 256 * 2;
    unsigned short* Wb1hi = (unsigned short*)w; w += (size_t)256 * 256 * 2;
    unsigned short* Wb1lo = (unsigned short*)w; w += (size_t)256 * 256 * 2;
    int*      rowp   = (int*)w;     w += (size_t)(N + 1) * 4;   // last (odd size)

    const int gN64  = (N + 63) / 64;
    const int gN4   = (N + 3) / 4;
    const int gNt   = (N + 255) / 256;
    const int gE    = (E + 255) / 256;
    const int gEN   = (EN + 255) / 256;
    const int nb    = (N + 1023) / 1024;

    // ---------------- one-time prep: W repack + deg_init (fused), CSR ----------------
    prep_kernel<<<384 + gNt, 256, 0, stream>>>(W0, Wb0hi, Wb0lo, W1, Wb1hi, Wb1lo, deg, N);
    deg_hist_kernel<<<gE, 256, 0, stream>>>(ei, E, deg);
    part_sum_kernel<<<nb, 256, 0, stream>>>(deg, bsum, N);
    scan_part_kernel<<<1, 256, 0, stream>>>(bsum, nb, rowp, N);
    distribute_kernel<<<nb, 256, 0, stream>>>(deg, bsum, rowp, cursor, N);
    scatter_kernel<<<gEN, 256, 0, stream>>>(ei, E, N, cursor, csr);

    // ---------------- layer 0 ----------------
    mfma_gemm0<<<gN64, 256, 0, stream>>>(x, Wb0hi, Wb0lo,
                                         as0, ad0, H, asrc, adst, N);
    agg4_kernel<false><<<gN4, 256, 0, stream>>>(rowp, csr, asrc, adst, H,
                                                b0, g0, be0, m0, v0,
                                                nullptr, P0, nullptr, nullptr, N);

    // ---------------- layer 1 (+ fused h2 = P1 . W2) ----------------
    mfma_gemm1<<<gN64, 256, 0, stream>>>(P0, Wb1hi, Wb1lo,
                                         as1, ad1, H, asrc, adst, N);
    agg4_kernel<true><<<gN4, 256, 0, stream>>>(rowp, csr, asrc, adst, H,
                                               b1, g1, be1, m1, v1,
                                               P0, nullptr, h2, W2, N);

    // ---------------- layer 2 ----------------
    agg2_kernel<<<gNt, 256, 0, stream>>>(rowp, csr, h2, as2, ad2, b2, (float*)d_out, N);
}